// Round 12
// baseline (99.350 us; speedup 1.0000x reference)
//
#include <hip/hip_runtime.h>

#define D 64
#define BSHIFT 7
#define NPB 128              // nodes per partition bucket (region granularity)
#define NBMAX 512            // max 128-node buckets
#define CAP 8192             // u32 dst-packed slots per bucket region
#define CAP2 8192            // u16 csr slots per bucket
#define A_TILE 4096          // edges per partition block (512 thr x 8)
#define ECAP CAP
#define EPT (ECAP / 512)     // 16 edges/thread/chunk
#define ZPAD 2               // extra hw rows (zero row at index n_nodes)
#define GSTRIDE 16           // one 64B line per bin cursor (atomic depth 6448->403)
#define SENT 0xFFFFFFFFu

__device__ __forceinline__ unsigned short f2bf(float f) {
    unsigned int u = __float_as_uint(f);
    u += 0x7FFFu + ((u >> 16) & 1u);     // RNE
    return (unsigned short)(u >> 16);
}
__device__ __forceinline__ float bflo(unsigned int w) {
    return __uint_as_float(w << 16);
}
__device__ __forceinline__ float bfhi(unsigned int w) {
    return __uint_as_float(w & 0xFFFF0000u);
}

// ---- K-1: zero counter head (must precede fused prep+partition) ----
__global__ __launch_bounds__(512) void zero_head_kernel(int* __restrict__ z, int n) {
    int i = blockIdx.x * 512 + threadIdx.x;
    if (i < n) z[i] = 0;
}

// ---- K0 (modes 0/1): zero counter ranges + hW = h @ W, bf16 two halves ----
__global__ __launch_bounds__(512) void prep_hw_kernel(
    const float* __restrict__ h, const float* __restrict__ W,
    unsigned short* __restrict__ hw,
    int* __restrict__ z1, int zc1, int* __restrict__ z2, int zc2,
    int n_nodes) {
    int t = threadIdx.x;
    int gid = blockIdx.x * 512 + t;
    for (int i = gid; i < zc1; i += gridDim.x * 512) z1[i] = 0;
    for (int i = gid; i < zc2; i += gridDim.x * 512) z2[i] = 0;
    int S = n_nodes + ZPAD;
    if (gid < 16) {
        ((unsigned int*)hw)[(size_t)n_nodes * 16 + gid] = 0u;
    } else if (gid < 32) {
        ((unsigned int*)hw)[(size_t)S * 16 + (size_t)n_nodes * 16 + (gid - 16)] = 0u;
    }
    int lane = t & 63;
    int wv = __builtin_amdgcn_readfirstlane(t >> 6);
    float wcol[D];
    #pragma unroll
    for (int k = 0; k < D; ++k) wcol[k] = W[k * D + lane];
    unsigned short* half0 = hw;
    unsigned short* half1 = hw + (size_t)S * 32;
    int row0 = (blockIdx.x * 8 + wv) * 4;
    if (row0 >= n_nodes) return;
    const float4* hr = (const float4*)(h + (size_t)row0 * D);   // wave-uniform
    float a0a = 0.f, a0b = 0.f, a1a = 0.f, a1b = 0.f;
    float a2a = 0.f, a2b = 0.f, a3a = 0.f, a3b = 0.f;
    if (row0 + 4 <= n_nodes) {
        #pragma unroll
        for (int k4 = 0; k4 < 16; ++k4) {
            float4 v0 = hr[k4];
            float4 v1 = hr[16 + k4];
            float4 v2 = hr[32 + k4];
            float4 v3 = hr[48 + k4];
            a0a = fmaf(v0.x, wcol[4*k4+0], a0a); a0b = fmaf(v0.y, wcol[4*k4+1], a0b);
            a0a = fmaf(v0.z, wcol[4*k4+2], a0a); a0b = fmaf(v0.w, wcol[4*k4+3], a0b);
            a1a = fmaf(v1.x, wcol[4*k4+0], a1a); a1b = fmaf(v1.y, wcol[4*k4+1], a1b);
            a1a = fmaf(v1.z, wcol[4*k4+2], a1a); a1b = fmaf(v1.w, wcol[4*k4+3], a1b);
            a2a = fmaf(v2.x, wcol[4*k4+0], a2a); a2b = fmaf(v2.y, wcol[4*k4+1], a2b);
            a2a = fmaf(v2.z, wcol[4*k4+2], a2a); a2b = fmaf(v2.w, wcol[4*k4+3], a2b);
            a3a = fmaf(v3.x, wcol[4*k4+0], a3a); a3b = fmaf(v3.y, wcol[4*k4+1], a3b);
            a3a = fmaf(v3.z, wcol[4*k4+2], a3a); a3b = fmaf(v3.w, wcol[4*k4+3], a3b);
        }
        unsigned short r0 = f2bf(a0a + a0b);
        unsigned short r1 = f2bf(a1a + a1b);
        unsigned short r2 = f2bf(a2a + a2b);
        unsigned short r3 = f2bf(a3a + a3b);
        if (lane < 32) {
            half0[(size_t)(row0 + 0) * 32 + lane] = r0;
            half0[(size_t)(row0 + 1) * 32 + lane] = r1;
            half0[(size_t)(row0 + 2) * 32 + lane] = r2;
            half0[(size_t)(row0 + 3) * 32 + lane] = r3;
        } else {
            half1[(size_t)(row0 + 0) * 32 + lane - 32] = r0;
            half1[(size_t)(row0 + 1) * 32 + lane - 32] = r1;
            half1[(size_t)(row0 + 2) * 32 + lane - 32] = r2;
            half1[(size_t)(row0 + 3) * 32 + lane - 32] = r3;
        }
    } else {
        for (int r = 0; r < 4; ++r) {
            int row = row0 + r;
            if (row >= n_nodes) break;
            float aa = 0.f, ab = 0.f;
            #pragma unroll
            for (int k4 = 0; k4 < 16; ++k4) {
                float4 v = hr[r * 16 + k4];
                aa = fmaf(v.x, wcol[4*k4+0], aa); ab = fmaf(v.y, wcol[4*k4+1], ab);
                aa = fmaf(v.z, wcol[4*k4+2], aa); ab = fmaf(v.w, wcol[4*k4+3], ab);
            }
            unsigned short val = f2bf(aa + ab);
            if (lane < 32) half0[(size_t)row * 32 + lane] = val;
            else           half1[(size_t)row * 32 + lane - 32] = val;
        }
    }
}

// ---- K1 (modes 0/1): standalone double-bin partition (legacy LDS-sort form) ----
__global__ __launch_bounds__(512) void partition_kernel(
    const int* __restrict__ src, const int* __restrict__ dst,
    int* __restrict__ hs, int* __restrict__ gcursor, int* __restrict__ gcursor2,
    unsigned int* __restrict__ gp_main, unsigned int* __restrict__ gp_last,
    unsigned short* __restrict__ srcpk,
    int* __restrict__ ofl_cnt, unsigned int* __restrict__ ofl, int ofl_cap,
    int* __restrict__ ofl2_cnt, unsigned int* __restrict__ ofl2, int ofl2_cap,
    int nb, int n_edges, int degmode) {
    __shared__ int lcnt[NBMAX], lbase[NBMAX], lcur[NBMAX], lgres[NBMAX];
    __shared__ int mcnt[NBMAX], mbase[NBMAX], mcur[NBMAX], mgres[NBMAX];
    __shared__ unsigned int sbuf[A_TILE];
    __shared__ unsigned short sbuf2[A_TILE];
    __shared__ int ltot, mtot;
    int t = threadIdx.x;
    int tile = blockIdx.x * A_TILE;

    lcnt[t] = 0; mcnt[t] = 0;
    if (t == 0) { ltot = 0; mtot = 0; }

    int s[8], d[8];
    int e0 = tile + t * 8;
    #pragma unroll
    for (int j = 0; j < 2; ++j) {
        int e = e0 + j * 4;
        if (e + 3 < n_edges) {
            int4 sv = *(const int4*)(src + e);
            int4 dv = *(const int4*)(dst + e);
            s[j*4+0] = sv.x; s[j*4+1] = sv.y; s[j*4+2] = sv.z; s[j*4+3] = sv.w;
            d[j*4+0] = dv.x; d[j*4+1] = dv.y; d[j*4+2] = dv.z; d[j*4+3] = dv.w;
        } else {
            #pragma unroll
            for (int k = 0; k < 4; ++k) {
                int ee = e + k;
                s[j*4+k] = (ee < n_edges) ? src[ee] : -1;
                d[j*4+k] = (ee < n_edges) ? dst[ee] : -1;
            }
        }
    }
    __syncthreads();
    #pragma unroll
    for (int j = 0; j < 8; ++j) {
        if (d[j] >= 0) {
            atomicAdd(&lcnt[d[j] >> BSHIFT], 1);
            if (degmode == 1) atomicAdd(&mcnt[s[j] >> BSHIFT], 1);
            else              atomicAdd(&hs[s[j]], 1);
        }
    }
    __syncthreads();
    int c  = lcnt[t];
    int c2 = mcnt[t];
    int rc  = (c  + 15) & ~15;
    int rc2 = (c2 + 15) & ~15;
    int gr = 0, gr2 = 0;
    if (c  > 0) gr  = atomicAdd(&gcursor[(size_t)t * GSTRIDE],  rc);
    if (c2 > 0) gr2 = atomicAdd(&gcursor2[(size_t)t * GSTRIDE], rc2);
    int lb  = (c  > 0) ? atomicAdd(&ltot, c)  : 0;
    int lb2 = (c2 > 0) ? atomicAdd(&mtot, c2) : 0;
    lbase[t] = lb;  lcur[t] = lb;
    mbase[t] = lb2; mcur[t] = lb2;
    __syncthreads();
    #pragma unroll
    for (int j = 0; j < 8; ++j) {
        if (d[j] >= 0) {
            int bin = d[j] >> BSHIFT;
            int pos = atomicAdd(&lcur[bin], 1);
            sbuf[pos] = ((unsigned int)d[j] << 16) | (unsigned int)s[j];
            if (degmode == 1) {
                int sbin = s[j] >> BSHIFT;
                int pos2 = atomicAdd(&mcur[sbin], 1);
                sbuf2[pos2] = (unsigned short)s[j];
            }
        }
    }
    lgres[t] = gr; mgres[t] = gr2;
    __syncthreads();
    int m = ltot;
    for (int pos = t; pos < m; pos += 512) {
        unsigned int p = sbuf[pos];
        int bin = (int)(p >> (16 + BSHIFT));
        int gidx = lgres[bin] + (pos - lbase[bin]);
        if (gidx < CAP) {
            unsigned int* gp = (bin == nb - 1) ? gp_last : (gp_main + (size_t)bin * CAP);
            gp[gidx] = p;
        } else {
            int op = atomicAdd(ofl_cnt, 1);
            if (op < ofl_cap) ofl[op] = p;
        }
    }
    int m2 = mtot;
    for (int pos = t; pos < m2; pos += 512) {
        unsigned short v = sbuf2[pos];
        int bin = (int)(v >> BSHIFT);
        int gidx = mgres[bin] + (pos - mbase[bin]);
        if (gidx < CAP2) {
            srcpk[(size_t)bin * CAP2 + gidx] = v;
        } else {
            int op = atomicAdd(ofl2_cnt, 1);
            if (op < ofl2_cap) ofl2[op] = (unsigned int)v;
        }
    }
    for (int i = c; i < rc; ++i) {
        int g = gr + i;
        if (g < CAP) {
            unsigned int* gp = (t == nb - 1) ? gp_last : (gp_main + (size_t)t * CAP);
            gp[g] = SENT;
        }
    }
    for (int i = c2; i < rc2; ++i) {
        int g = gr2 + i;
        if (g < CAP2) srcpk[(size_t)t * CAP2 + g] = 0xFFFFu;
    }
}

// ---- K0+K1 fused (mode 2): partition-first role order + LINE-PADDED cursors.
// R11 isolated the invariant ~26us: gcursor[0..390] spans ~25 lines, each
// receiving 403x16 same-line atomic RMWs (serialize ~4ns each at TCC).
// GSTRIDE=16 puts each bin cursor on its own 64B line -> depth 403/line.
__global__ __launch_bounds__(512) void fused_prep_part_kernel(
    const float* __restrict__ h, const float* __restrict__ W,
    unsigned short* __restrict__ hw, int n_nodes,
    const int* __restrict__ src, const int* __restrict__ dst,
    int* __restrict__ gcursor, int* __restrict__ gcursor2,
    unsigned int* __restrict__ gp_main, unsigned int* __restrict__ gp_last,
    unsigned short* __restrict__ srcpk,
    int* __restrict__ ofl_cnt, unsigned int* __restrict__ ofl, int ofl_cap,
    int* __restrict__ ofl2_cnt, unsigned int* __restrict__ ofl2, int ofl2_cap,
    int nb, int n_edges, int ab, int grid_total) {
    __shared__ int lcnt[NBMAX], ldel[NBMAX];
    __shared__ int mcnt[NBMAX], mdel[NBMAX];
    __shared__ unsigned int sbuf[A_TILE];
    __shared__ unsigned short sbuf2[A_TILE];
    __shared__ int ltot, mtot;
    int t = threadIdx.x;
    int bid = blockIdx.x;
    if (bid < ab) {
        // ---------------- partition role, tile bid ----------------
        int tile = bid * A_TILE;
        lcnt[t] = 0; mcnt[t] = 0;
        if (t == 0) { ltot = 0; mtot = 0; }
        int s[8], d[8];
        int e0 = tile + t * 8;
        #pragma unroll
        for (int j = 0; j < 2; ++j) {
            int e = e0 + j * 4;
            if (e + 3 < n_edges) {
                int4 sv = *(const int4*)(src + e);
                int4 dv = *(const int4*)(dst + e);
                s[j*4+0] = sv.x; s[j*4+1] = sv.y; s[j*4+2] = sv.z; s[j*4+3] = sv.w;
                d[j*4+0] = dv.x; d[j*4+1] = dv.y; d[j*4+2] = dv.z; d[j*4+3] = dv.w;
            } else {
                #pragma unroll
                for (int k = 0; k < 4; ++k) {
                    int ee = e + k;
                    s[j*4+k] = (ee < n_edges) ? src[ee] : -1;
                    d[j*4+k] = (ee < n_edges) ? dst[ee] : -1;
                }
            }
        }
        __syncthreads();
        #pragma unroll
        for (int j = 0; j < 8; ++j) {
            if (d[j] >= 0) {
                atomicAdd(&lcnt[d[j] >> BSHIFT], 1);
                atomicAdd(&mcnt[s[j] >> BSHIFT], 1);
            }
        }
        __syncthreads();
        int c  = lcnt[t];
        int c2 = mcnt[t];
        int rc  = (c  + 15) & ~15;
        int rc2 = (c2 + 15) & ~15;
        int gr = 0, gr2 = 0;
        if (c  > 0) gr  = atomicAdd(&gcursor[(size_t)t * GSTRIDE],  rc);
        if (c2 > 0) gr2 = atomicAdd(&gcursor2[(size_t)t * GSTRIDE], rc2);
        int lb  = (c  > 0) ? atomicAdd(&ltot, c)  : 0;
        int lb2 = (c2 > 0) ? atomicAdd(&mtot, c2) : 0;
        // reuse lcnt/mcnt as sort cursors; ldel/mdel = LDS->global index shift.
        lcnt[t] = lb;  ldel[t] = gr - lb;
        mcnt[t] = lb2; mdel[t] = gr2 - lb2;
        __syncthreads();
        #pragma unroll
        for (int j = 0; j < 8; ++j) {
            if (d[j] >= 0) {
                int bin = d[j] >> BSHIFT;
                int pos = atomicAdd(&lcnt[bin], 1);
                sbuf[pos] = ((unsigned int)d[j] << 16) | (unsigned int)s[j];
                int sbin = s[j] >> BSHIFT;
                int pos2 = atomicAdd(&mcnt[sbin], 1);
                sbuf2[pos2] = (unsigned short)s[j];
            }
        }
        __syncthreads();
        int m = ltot;
        for (int pos = t; pos < m; pos += 512) {
            unsigned int p = sbuf[pos];
            int bin = (int)(p >> (16 + BSHIFT));
            int gidx = pos + ldel[bin];
            if (gidx < CAP) {
                unsigned int* gp = (bin == nb - 1) ? gp_last : (gp_main + (size_t)bin * CAP);
                gp[gidx] = p;
            } else {
                int op = atomicAdd(ofl_cnt, 1);
                if (op < ofl_cap) ofl[op] = p;
            }
        }
        int m2 = mtot;
        for (int pos = t; pos < m2; pos += 512) {
            unsigned short v = sbuf2[pos];
            int bin = (int)(v >> BSHIFT);
            int gidx = pos + mdel[bin];
            if (gidx < CAP2) {
                srcpk[(size_t)bin * CAP2 + gidx] = v;
            } else {
                int op = atomicAdd(ofl2_cnt, 1);
                if (op < ofl2_cap) ofl2[op] = (unsigned int)v;
            }
        }
        for (int i = c; i < rc; ++i) {
            int g = gr + i;
            if (g < CAP) {
                unsigned int* gp = (t == nb - 1) ? gp_last : (gp_main + (size_t)t * CAP);
                gp[g] = SENT;
            }
        }
        for (int i = c2; i < rc2; ++i) {
            int g = gr2 + i;
            if (g < CAP2) srcpk[(size_t)t * CAP2 + g] = 0xFFFFu;
        }
    } else {
        // ---------------- prep role, prep_idx = bid - ab ----------------
        int prep_idx = bid - ab;
        int gid = prep_idx * 512 + t;
        int S = n_nodes + ZPAD;
        if (gid < 16) {
            ((unsigned int*)hw)[(size_t)n_nodes * 16 + gid] = 0u;
        } else if (gid < 32) {
            ((unsigned int*)hw)[(size_t)S * 16 + (size_t)n_nodes * 16 + (gid - 16)] = 0u;
        }
        int lane = t & 63;
        int wv = __builtin_amdgcn_readfirstlane(t >> 6);
        float wcol[D];
        #pragma unroll
        for (int k = 0; k < D; ++k) wcol[k] = W[k * D + lane];
        unsigned short* half0 = hw;
        unsigned short* half1 = hw + (size_t)S * 32;
        int row0 = (prep_idx * 8 + wv) * 4;
        if (row0 >= n_nodes) return;
        const float4* hr = (const float4*)(h + (size_t)row0 * D);   // wave-uniform
        float a0a = 0.f, a0b = 0.f, a1a = 0.f, a1b = 0.f;
        float a2a = 0.f, a2b = 0.f, a3a = 0.f, a3b = 0.f;
        if (row0 + 4 <= n_nodes) {
            #pragma unroll
            for (int k4 = 0; k4 < 16; ++k4) {
                float4 v0 = hr[k4];
                float4 v1 = hr[16 + k4];
                float4 v2 = hr[32 + k4];
                float4 v3 = hr[48 + k4];
                a0a = fmaf(v0.x, wcol[4*k4+0], a0a); a0b = fmaf(v0.y, wcol[4*k4+1], a0b);
                a0a = fmaf(v0.z, wcol[4*k4+2], a0a); a0b = fmaf(v0.w, wcol[4*k4+3], a0b);
                a1a = fmaf(v1.x, wcol[4*k4+0], a1a); a1b = fmaf(v1.y, wcol[4*k4+1], a1b);
                a1a = fmaf(v1.z, wcol[4*k4+2], a1a); a1b = fmaf(v1.w, wcol[4*k4+3], a1b);
                a2a = fmaf(v2.x, wcol[4*k4+0], a2a); a2b = fmaf(v2.y, wcol[4*k4+1], a2b);
                a2a = fmaf(v2.z, wcol[4*k4+2], a2a); a2b = fmaf(v2.w, wcol[4*k4+3], a2b);
                a3a = fmaf(v3.x, wcol[4*k4+0], a3a); a3b = fmaf(v3.y, wcol[4*k4+1], a3b);
                a3a = fmaf(v3.z, wcol[4*k4+2], a3a); a3b = fmaf(v3.w, wcol[4*k4+3], a3b);
            }
            unsigned short r0 = f2bf(a0a + a0b);
            unsigned short r1 = f2bf(a1a + a1b);
            unsigned short r2 = f2bf(a2a + a2b);
            unsigned short r3 = f2bf(a3a + a3b);
            if (lane < 32) {
                half0[(size_t)(row0 + 0) * 32 + lane] = r0;
                half0[(size_t)(row0 + 1) * 32 + lane] = r1;
                half0[(size_t)(row0 + 2) * 32 + lane] = r2;
                half0[(size_t)(row0 + 3) * 32 + lane] = r3;
            } else {
                half1[(size_t)(row0 + 0) * 32 + lane - 32] = r0;
                half1[(size_t)(row0 + 1) * 32 + lane - 32] = r1;
                half1[(size_t)(row0 + 2) * 32 + lane - 32] = r2;
                half1[(size_t)(row0 + 3) * 32 + lane - 32] = r3;
            }
        } else {
            for (int r = 0; r < 4; ++r) {
                int row = row0 + r;
                if (row >= n_nodes) break;
                float aa = 0.f, ab2 = 0.f;
                #pragma unroll
                for (int k4 = 0; k4 < 16; ++k4) {
                    float4 v = hr[r * 16 + k4];
                    aa = fmaf(v.x, wcol[4*k4+0], aa); ab2 = fmaf(v.y, wcol[4*k4+1], ab2);
                    aa = fmaf(v.z, wcol[4*k4+2], aa); ab2 = fmaf(v.w, wcol[4*k4+3], ab2);
                }
                unsigned short val = f2bf(aa + ab2);
                if (lane < 32) half0[(size_t)row * 32 + lane] = val;
                else           half1[(size_t)row * 32 + lane - 32] = val;
            }
        }
    }
}

// ---- K1b (mode 1): out-degree from srcpk regions ----
__global__ __launch_bounds__(512) void deg_from_srcpk(
    const int* __restrict__ gcursor2, const unsigned short* __restrict__ srcpk,
    const int* __restrict__ ofl2_cnt_p, const unsigned int* __restrict__ ofl2, int ofl2_cap,
    int* __restrict__ deg, int nb, int n_nodes) {
    __shared__ int hist[NPB];
    int t = threadIdx.x;
    int b = blockIdx.x;
    if (t < NPB) hist[t] = 0;
    __syncthreads();
    int cnt2 = gcursor2[(size_t)b * GSTRIDE]; if (cnt2 > CAP2) cnt2 = CAP2;
    const unsigned short* r2 = srcpk + (size_t)b * CAP2;
    for (int i = t; i < cnt2; i += 512) {
        unsigned short v = r2[i];
        if (v != 0xFFFFu) atomicAdd(&hist[v & (NPB - 1)], 1);
    }
    int n2 = *ofl2_cnt_p; if (n2 < 0) n2 = 0; if (n2 > ofl2_cap) n2 = ofl2_cap;
    for (int i = t; i < n2; i += 512) {
        unsigned int v = ofl2[i];
        if ((int)(v >> BSHIFT) == b) atomicAdd(&hist[v & (NPB - 1)], 1);
    }
    __syncthreads();
    if (t < NPB) {
        int node = b * NPB + t;
        if (node < n_nodes) deg[node] = hist[t];
    }
}

// ---- K1b+K1c fused (mode 2): deg hist + node-sorted padded CSR, one block/bucket ----
__global__ __launch_bounds__(512) void fused_deg_csr_kernel(
    const int* __restrict__ gcursor2, const unsigned short* __restrict__ srcpk,
    const int* __restrict__ ofl2_cnt_p, const unsigned int* __restrict__ ofl2, int ofl2_cap,
    int* __restrict__ deg,
    const int* __restrict__ gcursor,
    const unsigned int* gp_main, const unsigned int* gp_last,
    const int* __restrict__ ofl_cnt_p, const unsigned int* __restrict__ ofl, int ofl_cap,
    unsigned short* __restrict__ gcsr,
    int* __restrict__ nodeoff, int* __restrict__ nodecnt,
    int nb, int n_nodes) {
    __shared__ int hist[NPB];
    __shared__ int lcnt[NPB], loff[NPB], lcur[NPB], lpc[NPB];
    __shared__ unsigned short csr[CAP2];
    int t = threadIdx.x;
    int lane = t & 63;
    int wv = t >> 6;
    int b = blockIdx.x;

    if (t < NPB) { hist[t] = 0; lcnt[t] = 0; }
    __syncthreads();

    int cnt2 = gcursor2[(size_t)b * GSTRIDE]; if (cnt2 > CAP2) cnt2 = CAP2;
    const unsigned short* r2 = srcpk + (size_t)b * CAP2;
    for (int i = t; i < cnt2; i += 512) {
        unsigned short v = r2[i];
        if (v != 0xFFFFu) atomicAdd(&hist[v & (NPB - 1)], 1);
    }
    int n2 = *ofl2_cnt_p; if (n2 < 0) n2 = 0; if (n2 > ofl2_cap) n2 = ofl2_cap;
    for (int i = t; i < n2; i += 512) {
        unsigned int v = ofl2[i];
        if ((int)(v >> BSHIFT) == b) atomicAdd(&hist[v & (NPB - 1)], 1);
    }

    const unsigned int* region = (b == nb - 1) ? gp_last : (gp_main + (size_t)b * CAP);
    int cnt = gcursor[(size_t)b * GSTRIDE]; if (cnt > CAP) cnt = CAP;
    int ofn = *ofl_cnt_p; if (ofn < 0) ofn = 0; if (ofn > ofl_cap) ofn = ofl_cap;
    unsigned int ep[EPT];
    #pragma unroll
    for (int u = 0; u < EPT; ++u) {
        int i = t + u * 512;
        ep[u] = (i < cnt) ? region[i] : SENT;
    }
    #pragma unroll
    for (int u = 0; u < EPT; ++u) {
        if (ep[u] != SENT && (int)(ep[u] >> (16 + BSHIFT)) == b)
            atomicAdd(&lcnt[(ep[u] >> 16) & (NPB - 1)], 1);
        else ep[u] = SENT;
    }
    for (int i = t; i < ofn; i += 512) {
        unsigned int p = ofl[i];
        if ((int)(p >> (16 + BSHIFT)) == b)
            atomicAdd(&lcnt[(p >> 16) & (NPB - 1)], 1);
    }
    __syncthreads();

    if (t < NPB) {
        int node = b * NPB + t;
        if (node < n_nodes) deg[node] = hist[t];
    }

    if (wv == 0) {
        int c0 = lcnt[lane];
        int c1 = lcnt[lane + 64];
        int p0 = (c0 + 15) & ~15;
        int p1 = (c1 + 15) & ~15;
        int sm = p0 + p1;
        int x = sm;
        #pragma unroll
        for (int o = 1; o < 64; o <<= 1) {
            int y = __shfl_up(x, o);
            if (lane >= o) x += y;
        }
        int base = x - sm;
        loff[lane] = base;            lcur[lane] = base;            lpc[lane] = p0;
        loff[lane + 64] = base + p0;  lcur[lane + 64] = base + p0;  lpc[lane + 64] = p1;
    }
    __syncthreads();
    if (t < NPB) {
        nodeoff[(size_t)b * NPB + t] = loff[t];
        nodecnt[(size_t)b * NPB + t] = lpc[t];
    }
    #pragma unroll
    for (int u = 0; u < EPT; ++u) {
        if (ep[u] != SENT) {
            int nl = (int)((ep[u] >> 16) & (NPB - 1));
            int pos = atomicAdd(&lcur[nl], 1);
            if (pos < CAP2) csr[pos] = (unsigned short)(ep[u] & 0xFFFFu);
        }
    }
    for (int i = t; i < ofn; i += 512) {
        unsigned int p = ofl[i];
        if ((int)(p >> (16 + BSHIFT)) == b) {
            int nl = (int)((p >> 16) & (NPB - 1));
            int pos = atomicAdd(&lcur[nl], 1);
            if (pos < CAP2) csr[pos] = (unsigned short)(p & 0xFFFFu);
        }
    }
    __syncthreads();
    if (t < NPB) {                                 // zero-row padding fill
        int i0 = loff[t] + lcnt[t];
        int i1 = loff[t] + lpc[t];
        for (int i = i0; i < i1; ++i)
            if (i < CAP2) csr[i] = (unsigned short)n_nodes;
    }
    __syncthreads();
    int tot = loff[NPB - 1] + lpc[NPB - 1];
    if (tot > CAP2) tot = CAP2;
    unsigned int* gc = (unsigned int*)(gcsr + (size_t)b * CAP2);
    const unsigned int* lc4 = (const unsigned int*)csr;
    for (int i = t; i < (tot + 1) / 2; i += 512) gc[i] = lc4[i];
}

// ---- K2 (mode 2): predicate-free CSR gather; BOTH passes in one dispatch ----
__global__ __launch_bounds__(512, 2) void gather_csr_kernel(
    const unsigned short* __restrict__ hw, const float* __restrict__ bias,
    const int* __restrict__ degarr,
    const unsigned short* __restrict__ gcsr,
    const int* __restrict__ nodeoff, const int* __restrict__ nodecnt,
    int nb, float* __restrict__ out, int n_nodes) {
    __shared__ unsigned short csr[CAP2];
    __shared__ int lo[32], lc[32];
    int t = threadIdx.x;
    int lane = t & 63;
    int wv = t >> 6;
    int g = lane >> 3;
    int l8 = lane & 7;
    int blk = blockIdx.x;
    int half_n = nb * 4;
    int pass = (blk >= half_n) ? 1 : 0;
    int r = blk - pass * half_n;
    int b = r >> 2;
    int hh = r & 3;
    int S = n_nodes + ZPAD;

    int idx0 = b * NPB + hh * 32;
    int base = nodeoff[idx0];
    int end  = nodeoff[idx0 + 31] + nodecnt[idx0 + 31];
    if (base > CAP2) base = CAP2;
    if (end > CAP2) end = CAP2;
    int len = end - base; if (len < 0) len = 0;
    const unsigned int* gc = (const unsigned int*)(gcsr + (size_t)b * CAP2 + base);
    unsigned int* lc4 = (unsigned int*)csr;
    for (int i = t; i < (len + 1) / 2; i += 512) lc4[i] = gc[i];
    if (t < 32) {
        int idx = idx0 + t;
        int off = nodeoff[idx] - base;
        int pc = nodecnt[idx];
        if (off < 0) off = 0;
        if (off > len) off = len;
        if (pc > len - off) pc = (len - off) & ~15;
        if (pc < 0) pc = 0;
        lo[t] = off; lc[t] = pc;
    }
    __syncthreads();

    int pair = wv * 4 + (g >> 1);
    int off = lo[pair];
    int pc = lc[pair];
    float acc[4];
    acc[0] = acc[1] = acc[2] = acc[3] = 0.f;

    const uint2* hwh = (const uint2*)(hw + (size_t)pass * S * 32);
    for (int j = (g & 1) * 8; j < pc; j += 16) {
        uint2 v[8];
        #pragma unroll
        for (int u = 0; u < 8; ++u) {
            int ss = (int)csr[off + j + u];
            v[u] = hwh[(unsigned)(ss * 8 + l8)];
        }
        #pragma unroll
        for (int u = 0; u < 8; ++u) {
            acc[0] += bflo(v[u].x); acc[1] += bfhi(v[u].x);
            acc[2] += bflo(v[u].y); acc[3] += bfhi(v[u].y);
        }
    }

    #pragma unroll
    for (int q = 0; q < 4; ++q)
        acc[q] += __shfl_xor(acc[q], 8);

    if (!(g & 1)) {
        int node = b * NPB + hh * 32 + pair;
        if (node < n_nodes) {
            float4 bv = ((const float4*)bias)[pass * 8 + l8];
            float nrm = rsqrtf((float)degarr[node]);
            float4 rr;
            rr.x = fmaxf(fmaf(acc[0], nrm, bv.x), 0.f);
            rr.y = fmaxf(fmaf(acc[1], nrm, bv.y), 0.f);
            rr.z = fmaxf(fmaf(acc[2], nrm, bv.z), 0.f);
            rr.w = fmaxf(fmaf(acc[3], nrm, bv.w), 0.f);
            ((float4*)out)[(size_t)node * 16 + pass * 8 + l8] = rr;
        }
    }
}

// ---- old combined gather (modes 0/1 only) ----
template<int NLOC>
__global__ __launch_bounds__(512, 2) void bucket_gather_t(
    const unsigned short* __restrict__ hw, const float* __restrict__ bias,
    const int* __restrict__ gcursor, const int* __restrict__ degarr,
    const unsigned int* gp_main, const unsigned int* gp_last,  // may alias out
    const int* __restrict__ ofl_cnt_p, const unsigned int* __restrict__ ofl, int ofl_cap,
    int nb, float* out, int n_nodes) {
    constexpr int SPB = NPB / NLOC;
    __shared__ int lcnt[NLOC];
    __shared__ int loff[NLOC];
    __shared__ int lcur[NLOC];
    __shared__ unsigned short csr[ECAP];
    int t = threadIdx.x;
    int lane = t & 63;
    int wv = t >> 6;
    int g = lane >> 3;
    int l8 = lane & 7;
    int blk = blockIdx.x;
    int b = blk / SPB;
    int hh = blk % SPB;
    int S = n_nodes + ZPAD;
    const unsigned int* region = (b == nb - 1) ? gp_last : (gp_main + (size_t)b * CAP);
    int cnt = gcursor[(size_t)b * GSTRIDE]; if (cnt > CAP) cnt = CAP;
    int ofn = *ofl_cnt_p; if (ofn < 0) ofn = 0; if (ofn > ofl_cap) ofn = ofl_cap;

    constexpr int KN = NLOC / 64;
    float acc[KN][2][4];
    #pragma unroll
    for (int k = 0; k < KN; ++k)
        #pragma unroll
        for (int p = 0; p < 2; ++p)
            #pragma unroll
            for (int q = 0; q < 4; ++q) acc[k][p][q] = 0.f;

    int nch = 1 + ((ofn > 0) ? (ofn + ECAP - 1) / ECAP : 0);
    for (int ch = 0; ch < nch; ++ch) {
        const unsigned int* sp; int m;
        if (ch == 0) { sp = region; m = cnt; }
        else {
            sp = ofl + (size_t)(ch - 1) * ECAP;
            m = ofn - (ch - 1) * ECAP; if (m > ECAP) m = ECAP;
        }
        if (t < NLOC) lcnt[t] = 0;
        __syncthreads();
        unsigned int ep[EPT];
        #pragma unroll
        for (int u = 0; u < EPT; ++u) {
            int i = t + u * 512;
            ep[u] = (i < m) ? sp[i] : SENT;
        }
        #pragma unroll
        for (int u = 0; u < EPT; ++u) {
            if (ep[u] != SENT) {
                int pb = (int)(ep[u] >> (16 + BSHIFT));
                int nl_r = (int)((ep[u] >> 16) & (NPB - 1));
                if (pb != b || (SPB == 2 && ((nl_r >> 6) != hh))) ep[u] = SENT;
            }
        }
        #pragma unroll
        for (int u = 0; u < EPT; ++u)
            if (ep[u] != SENT)
                atomicAdd(&lcnt[(ep[u] >> 16) & (NLOC - 1)], 1);
        __syncthreads();
        if (wv == 0) {
            if (NLOC == 128) {
                int v0 = lcnt[lane];
                int v1 = lcnt[lane + 64];
                int sm = v0 + v1;
                int x = sm;
                #pragma unroll
                for (int o = 1; o < 64; o <<= 1) {
                    int y = __shfl_up(x, o);
                    if (lane >= o) x += y;
                }
                int base = x - sm;
                loff[lane] = base;            lcur[lane] = base;
                loff[lane + 64] = base + v0;  lcur[lane + 64] = base + v0;
            } else {
                int v = lcnt[lane];
                int x = v;
                #pragma unroll
                for (int o = 1; o < 64; o <<= 1) {
                    int y = __shfl_up(x, o);
                    if (lane >= o) x += y;
                }
                loff[lane] = x - v;
                lcur[lane] = x - v;
            }
        }
        __syncthreads();
        #pragma unroll
        for (int u = 0; u < EPT; ++u)
            if (ep[u] != SENT) {
                int nl = (int)((ep[u] >> 16) & (NLOC - 1));
                int pos = atomicAdd(&lcur[nl], 1);
                csr[pos] = (unsigned short)(ep[u] & 0xFFFFu);
            }
        __syncthreads();
        #pragma unroll
        for (int p = 0; p < 2; ++p) {
            const uint2* hwh = (const uint2*)(hw + (size_t)p * S * 32);
            #pragma unroll
            for (int k = 0; k < KN; ++k) {
                int nl = k * 64 + wv * 8 + g;
                int off = loff[nl];
                int c = lcnt[nl];
                for (int j = 0; j < c; j += 8) {
                    uint2 v[8];
                    bool ok[8];
                    #pragma unroll
                    for (int u = 0; u < 8; ++u) {
                        int idx = j + u;
                        ok[u] = idx < c;
                        int ss = (int)csr[off + (ok[u] ? idx : 0)];
                        v[u] = ok[u] ? hwh[(size_t)ss * 8 + l8] : make_uint2(0, 0);
                    }
                    #pragma unroll
                    for (int u = 0; u < 8; ++u) {
                        acc[k][p][0] += bflo(v[u].x); acc[k][p][1] += bfhi(v[u].x);
                        acc[k][p][2] += bflo(v[u].y); acc[k][p][3] += bfhi(v[u].y);
                    }
                }
            }
        }
        __syncthreads();
    }

    float4 bv0 = ((const float4*)bias)[l8];
    float4 bv1 = ((const float4*)bias)[8 + l8];
    int node0 = b * NPB + hh * 64;
    #pragma unroll
    for (int k = 0; k < KN; ++k) {
        int nl = k * 64 + wv * 8 + g;
        int node = node0 + nl;
        if (node >= n_nodes) continue;
        float nrm = rsqrtf((float)degarr[node]);
        float4 r0, r1;
        r0.x = fmaxf(fmaf(acc[k][0][0], nrm, bv0.x), 0.f);
        r0.y = fmaxf(fmaf(acc[k][0][1], nrm, bv0.y), 0.f);
        r0.z = fmaxf(fmaf(acc[k][0][2], nrm, bv0.z), 0.f);
        r0.w = fmaxf(fmaf(acc[k][0][3], nrm, bv0.w), 0.f);
        r1.x = fmaxf(fmaf(acc[k][1][0], nrm, bv1.x), 0.f);
        r1.y = fmaxf(fmaf(acc[k][1][1], nrm, bv1.y), 0.f);
        r1.z = fmaxf(fmaf(acc[k][1][2], nrm, bv1.z), 0.f);
        r1.w = fmaxf(fmaf(acc[k][1][3], nrm, bv1.w), 0.f);
        ((float4*)out)[(size_t)node * 16 + l8]     = r0;
        ((float4*)out)[(size_t)node * 16 + 8 + l8] = r1;
    }
}

// ---------------- fallback atomic path (if ws too small / shape odd) ----------------

__global__ void deg_kernel(const int* __restrict__ src, float* __restrict__ deg, int n_edges) {
    int e = blockIdx.x * blockDim.x + threadIdx.x;
    if (e < n_edges) atomicAdd(&deg[src[e]], 1.0f);
}

__global__ void scatter_kernel(const float* __restrict__ h, const int* __restrict__ src,
                               const int* __restrict__ dst, float* __restrict__ agg,
                               int n_edges) {
    long long tid = (long long)blockIdx.x * blockDim.x + threadIdx.x;
    int e = (int)(tid >> 6);
    int f = (int)(tid & 63);
    if (e < n_edges) {
        atomicAdd(&agg[(long long)dst[e] * D + f], h[(long long)src[e] * D + f]);
    }
}

__global__ void transform_kernel(float* __restrict__ agg_out, const float* __restrict__ W,
                                 const float* __restrict__ bias, const float* __restrict__ deg,
                                 int n_nodes) {
    __shared__ float w_lds[D][D];
    __shared__ float a_lds[4][D];
    __shared__ float b_lds[D];
    int t = threadIdx.x;
    for (int i = t; i < D * D; i += 256) w_lds[i >> 6][i & 63] = W[i];
    if (t < D) b_lds[t] = bias[t];
    int rl = t >> 6, col = t & 63;
    int row = blockIdx.x * 4 + rl;
    if (row < n_nodes) a_lds[rl][col] = agg_out[(long long)row * D + col];
    __syncthreads();
    if (row < n_nodes) {
        float sum = 0.f;
        #pragma unroll
        for (int k = 0; k < D; ++k) sum = fmaf(a_lds[rl][k], w_lds[k][col], sum);
        float v = fmaf(sum, rsqrtf(deg[row]), b_lds[col]);
        agg_out[(long long)row * D + col] = fmaxf(v, 0.f);
    }
}

extern "C" void kernel_launch(void* const* d_in, const int* in_sizes, int n_in,
                              void* d_out, int out_size, void* d_ws, size_t ws_size,
                              hipStream_t stream) {
    const float* h    = (const float*)d_in[0];
    const float* W    = (const float*)d_in[1];
    const float* bias = (const float*)d_in[2];
    const int*   src  = (const int*)d_in[3];
    const int*   dst  = (const int*)d_in[4];
    float* out = (float*)d_out;

    int n_nodes = in_sizes[0] / D;
    int n_edges = in_sizes[3];
    int nb = (n_nodes + NPB - 1) / NPB;

    bool shape_ok = (nb <= NBMAX - 1) && (n_nodes <= 65408) && (n_nodes % 2 == 0) &&
                    ((size_t)out_size == (size_t)n_nodes * D);
    size_t head = 2 * (size_t)NBMAX * GSTRIDE + 2;
    size_t hw_ints = (size_t)(n_nodes + ZPAD) * 32;   // two halves, (n+ZPAD) rows x 32 bf16
    // mode 2: regions in ws, csr path, srcpk deg, nodeoff/cnt
    size_t gp2   = (head + 3) & ~(size_t)3;
    size_t hw2s  = gp2 + (size_t)nb * CAP;
    size_t spk2  = hw2s + hw_ints;
    size_t csr2  = spk2 + (size_t)nb * (CAP2 / 2);    // separate csr store
    size_t ofl2s = csr2 + (size_t)nb * (CAP2 / 2);
    size_t of22s = ofl2s + 16384;
    size_t deg2  = of22s + 8192;
    size_t noff2 = deg2 + n_nodes;
    size_t ncnt2 = noff2 + (size_t)nb * NPB;
    size_t need2 = (ncnt2 + (size_t)nb * NPB) * 4;
    // mode 1: regions alias d_out
    size_t gpl1 = (head + 3) & ~(size_t)3;
    size_t hw1  = gpl1 + CAP;
    size_t spk1 = hw1 + hw_ints;
    size_t ofl1 = spk1 + (size_t)nb * (CAP2 / 2);
    size_t of21 = ofl1 + 16384;
    size_t deg1 = of21 + 8192;
    size_t need1 = (deg1 + n_nodes) * 4;
    // mode 0: legacy global hs, regions alias d_out
    size_t hs0  = head;
    size_t gpl0 = (hs0 + n_nodes + 3) & ~(size_t)3;
    size_t hw0  = gpl0 + CAP;
    size_t ofl0 = hw0 + hw_ints;
    size_t need0 = (ofl0 + 16384) * 4;

    if (shape_ok && ws_size >= need0) {
        int mode = (ws_size >= need2) ? 2 : ((ws_size >= need1) ? 1 : 0);
        int* wsI = (int*)d_ws;
        int* gcursor  = wsI;
        int* gcursor2 = wsI + (size_t)NBMAX * GSTRIDE;
        int* ofl_cnt  = wsI + 2 * (size_t)NBMAX * GSTRIDE;
        int* ofl2_cnt = wsI + 2 * (size_t)NBMAX * GSTRIDE + 1;
        unsigned int* gp_main; unsigned int* gp_last;
        unsigned short* hw; unsigned short* srcpk; unsigned short* gcsrp = 0;
        unsigned int* ofl; unsigned int* ofl2;
        int* degp; int* noffp = 0; int* ncntp = 0; int* hs;
        if (mode == 2) {
            gp_main = (unsigned int*)(wsI + gp2);
            gp_last = gp_main + (size_t)(nb - 1) * CAP;
            hw      = (unsigned short*)(wsI + hw2s);
            srcpk   = (unsigned short*)(wsI + spk2);
            gcsrp   = (unsigned short*)(wsI + csr2);
            ofl     = (unsigned int*)(wsI + ofl2s);
            ofl2    = (unsigned int*)(wsI + of22s);
            degp    = wsI + deg2;
            noffp   = wsI + noff2;
            ncntp   = wsI + ncnt2;
            hs      = gcursor;                   // dummy
        } else if (mode == 1) {
            gp_main = (unsigned int*)d_out;
            gp_last = (unsigned int*)(wsI + gpl1);
            hw      = (unsigned short*)(wsI + hw1);
            srcpk   = (unsigned short*)(wsI + spk1);
            ofl     = (unsigned int*)(wsI + ofl1);
            ofl2    = (unsigned int*)(wsI + of21);
            degp    = wsI + deg1;
            hs      = gcursor;                   // dummy (degmode==1)
        } else {
            gp_main = (unsigned int*)d_out;
            gp_last = (unsigned int*)(wsI + gpl0);
            hw      = (unsigned short*)(wsI + hw0);
            srcpk   = (unsigned short*)(wsI + gpl0);   // unused
            ofl     = (unsigned int*)(wsI + ofl0);
            ofl2    = (unsigned int*)(wsI + ofl0);     // unused
            degp    = wsI + hs0;
            hs      = degp;
        }
        int ofl_cap = 16384, ofl2_cap = (mode >= 1) ? 8192 : 0;

        int pb = (n_nodes + 31) / 32;            // 4 rows/wave x 8 waves
        int ab = (n_edges + A_TILE - 1) / A_TILE;

        if (mode == 2) {
            zero_head_kernel<<<(int)((head + 511) / 512), 512, 0, stream>>>(wsI, (int)head);
            int grid_total = pb + ab;
            fused_prep_part_kernel<<<grid_total, 512, 0, stream>>>(
                h, W, hw, n_nodes, src, dst, gcursor, gcursor2,
                gp_main, gp_last, srcpk,
                ofl_cnt, ofl, ofl_cap, ofl2_cnt, ofl2, ofl2_cap,
                nb, n_edges, ab, grid_total);
            fused_deg_csr_kernel<<<nb, 512, 0, stream>>>(
                gcursor2, srcpk, ofl2_cnt, ofl2, ofl2_cap, degp,
                gcursor, gp_main, gp_last, ofl_cnt, ofl, ofl_cap,
                gcsrp, noffp, ncntp, nb, n_nodes);
            gather_csr_kernel<<<nb * 8, 512, 0, stream>>>(
                hw, bias, degp, gcsrp, noffp, ncntp, nb, out, n_nodes);
        } else {
            int degmode = (mode >= 1) ? 1 : 0;
            int zc1 = (int)head;
            int zc2 = (mode >= 1) ? 0 : n_nodes;
            int* z2p = (mode >= 1) ? wsI : degp;
            prep_hw_kernel<<<pb, 512, 0, stream>>>(h, W, hw, wsI, zc1, z2p, zc2, n_nodes);
            partition_kernel<<<ab, 512, 0, stream>>>(src, dst, hs, gcursor, gcursor2,
                                                     gp_main, gp_last, srcpk,
                                                     ofl_cnt, ofl, ofl_cap,
                                                     ofl2_cnt, ofl2, ofl2_cap,
                                                     nb, n_edges, degmode);
            if (mode >= 1)
                deg_from_srcpk<<<nb, 512, 0, stream>>>(gcursor2, srcpk, ofl2_cnt, ofl2,
                                                       ofl2_cap, degp, nb, n_nodes);
            bucket_gather_t<128><<<nb, 512, 0, stream>>>(
                hw, bias, gcursor, degp, gp_main, gp_last,
                ofl_cnt, ofl, ofl_cap, nb, out, n_nodes);
        }
    } else {
        float* deg = (float*)d_ws;
        hipMemsetAsync(out, 0, (size_t)n_nodes * D * sizeof(float), stream);
        hipMemsetAsync(deg, 0, (size_t)n_nodes * sizeof(float), stream);
        int eb = (n_edges + 255) / 256;
        deg_kernel<<<eb, 256, 0, stream>>>(src, deg, n_edges);
        long long total = (long long)n_edges * D;
        scatter_kernel<<<(int)((total + 255) / 256), 256, 0, stream>>>(h, src, dst, out, n_edges);
        transform_kernel<<<(n_nodes + 3) / 4, 256, 0, stream>>>(out, W, bias, deg, n_nodes);
    }
}

// Round 13
// 80.665 us; speedup vs baseline: 1.2316x; 1.2316x over previous
//
#include <hip/hip_runtime.h>

#define D 64
#define BSHIFT 7
#define NPB 128              // nodes per partition bucket (region granularity)
#define NBMAX 512            // max 128-node buckets
#define CAP 8192             // u32 dst-packed slots per bucket region
#define CAP2 8192            // u16 csr slots per bucket
#define A_TILE 4096          // edges per partition block (512 thr x 8)
#define ECAP CAP
#define EPT (ECAP / 512)     // 16 edges/thread/chunk
#define ZPAD 2               // extra hw rows (zero row at index n_nodes)
#define SENT 0xFFFFFFFFu

__device__ __forceinline__ unsigned short f2bf(float f) {
    unsigned int u = __float_as_uint(f);
    u += 0x7FFFu + ((u >> 16) & 1u);     // RNE
    return (unsigned short)(u >> 16);
}
__device__ __forceinline__ float bflo(unsigned int w) {
    return __uint_as_float(w << 16);
}
__device__ __forceinline__ float bfhi(unsigned int w) {
    return __uint_as_float(w & 0xFFFF0000u);
}

// ---- K-1: zero counter head (must precede fused prep+partition) ----
__global__ __launch_bounds__(512) void zero_head_kernel(int* __restrict__ z, int n) {
    int i = blockIdx.x * 512 + threadIdx.x;
    if (i < n) z[i] = 0;
}

// ---- K0 (modes 0/1): zero counter ranges + hW = h @ W, bf16 two halves ----
__global__ __launch_bounds__(512) void prep_hw_kernel(
    const float* __restrict__ h, const float* __restrict__ W,
    unsigned short* __restrict__ hw,
    int* __restrict__ z1, int zc1, int* __restrict__ z2, int zc2,
    int n_nodes) {
    int t = threadIdx.x;
    int gid = blockIdx.x * 512 + t;
    for (int i = gid; i < zc1; i += gridDim.x * 512) z1[i] = 0;
    for (int i = gid; i < zc2; i += gridDim.x * 512) z2[i] = 0;
    int S = n_nodes + ZPAD;
    if (gid < 16) {
        ((unsigned int*)hw)[(size_t)n_nodes * 16 + gid] = 0u;
    } else if (gid < 32) {
        ((unsigned int*)hw)[(size_t)S * 16 + (size_t)n_nodes * 16 + (gid - 16)] = 0u;
    }
    int lane = t & 63;
    int wv = __builtin_amdgcn_readfirstlane(t >> 6);
    float wcol[D];
    #pragma unroll
    for (int k = 0; k < D; ++k) wcol[k] = W[k * D + lane];
    unsigned short* half0 = hw;
    unsigned short* half1 = hw + (size_t)S * 32;
    int row0 = (blockIdx.x * 8 + wv) * 4;
    if (row0 >= n_nodes) return;
    const float4* hr = (const float4*)(h + (size_t)row0 * D);   // wave-uniform
    float a0a = 0.f, a0b = 0.f, a1a = 0.f, a1b = 0.f;
    float a2a = 0.f, a2b = 0.f, a3a = 0.f, a3b = 0.f;
    if (row0 + 4 <= n_nodes) {
        #pragma unroll
        for (int k4 = 0; k4 < 16; ++k4) {
            float4 v0 = hr[k4];
            float4 v1 = hr[16 + k4];
            float4 v2 = hr[32 + k4];
            float4 v3 = hr[48 + k4];
            a0a = fmaf(v0.x, wcol[4*k4+0], a0a); a0b = fmaf(v0.y, wcol[4*k4+1], a0b);
            a0a = fmaf(v0.z, wcol[4*k4+2], a0a); a0b = fmaf(v0.w, wcol[4*k4+3], a0b);
            a1a = fmaf(v1.x, wcol[4*k4+0], a1a); a1b = fmaf(v1.y, wcol[4*k4+1], a1b);
            a1a = fmaf(v1.z, wcol[4*k4+2], a1a); a1b = fmaf(v1.w, wcol[4*k4+3], a1b);
            a2a = fmaf(v2.x, wcol[4*k4+0], a2a); a2b = fmaf(v2.y, wcol[4*k4+1], a2b);
            a2a = fmaf(v2.z, wcol[4*k4+2], a2a); a2b = fmaf(v2.w, wcol[4*k4+3], a2b);
            a3a = fmaf(v3.x, wcol[4*k4+0], a3a); a3b = fmaf(v3.y, wcol[4*k4+1], a3b);
            a3a = fmaf(v3.z, wcol[4*k4+2], a3a); a3b = fmaf(v3.w, wcol[4*k4+3], a3b);
        }
        unsigned short r0 = f2bf(a0a + a0b);
        unsigned short r1 = f2bf(a1a + a1b);
        unsigned short r2 = f2bf(a2a + a2b);
        unsigned short r3 = f2bf(a3a + a3b);
        if (lane < 32) {
            half0[(size_t)(row0 + 0) * 32 + lane] = r0;
            half0[(size_t)(row0 + 1) * 32 + lane] = r1;
            half0[(size_t)(row0 + 2) * 32 + lane] = r2;
            half0[(size_t)(row0 + 3) * 32 + lane] = r3;
        } else {
            half1[(size_t)(row0 + 0) * 32 + lane - 32] = r0;
            half1[(size_t)(row0 + 1) * 32 + lane - 32] = r1;
            half1[(size_t)(row0 + 2) * 32 + lane - 32] = r2;
            half1[(size_t)(row0 + 3) * 32 + lane - 32] = r3;
        }
    } else {
        for (int r = 0; r < 4; ++r) {
            int row = row0 + r;
            if (row >= n_nodes) break;
            float aa = 0.f, ab = 0.f;
            #pragma unroll
            for (int k4 = 0; k4 < 16; ++k4) {
                float4 v = hr[r * 16 + k4];
                aa = fmaf(v.x, wcol[4*k4+0], aa); ab = fmaf(v.y, wcol[4*k4+1], ab);
                aa = fmaf(v.z, wcol[4*k4+2], aa); ab = fmaf(v.w, wcol[4*k4+3], ab);
            }
            unsigned short val = f2bf(aa + ab);
            if (lane < 32) half0[(size_t)row * 32 + lane] = val;
            else           half1[(size_t)row * 32 + lane - 32] = val;
        }
    }
}

// ---- K1 (modes 0/1): standalone double-bin partition (legacy padded form) ----
__global__ __launch_bounds__(512) void partition_kernel(
    const int* __restrict__ src, const int* __restrict__ dst,
    int* __restrict__ hs, int* __restrict__ gcursor, int* __restrict__ gcursor2,
    unsigned int* __restrict__ gp_main, unsigned int* __restrict__ gp_last,
    unsigned short* __restrict__ srcpk,
    int* __restrict__ ofl_cnt, unsigned int* __restrict__ ofl, int ofl_cap,
    int* __restrict__ ofl2_cnt, unsigned int* __restrict__ ofl2, int ofl2_cap,
    int nb, int n_edges, int degmode) {
    __shared__ int lcnt[NBMAX], lbase[NBMAX], lcur[NBMAX], lgres[NBMAX];
    __shared__ int mcnt[NBMAX], mbase[NBMAX], mcur[NBMAX], mgres[NBMAX];
    __shared__ unsigned int sbuf[A_TILE];
    __shared__ unsigned short sbuf2[A_TILE];
    __shared__ int ltot, mtot;
    int t = threadIdx.x;
    int tile = blockIdx.x * A_TILE;

    lcnt[t] = 0; mcnt[t] = 0;
    if (t == 0) { ltot = 0; mtot = 0; }

    int s[8], d[8];
    int e0 = tile + t * 8;
    #pragma unroll
    for (int j = 0; j < 2; ++j) {
        int e = e0 + j * 4;
        if (e + 3 < n_edges) {
            int4 sv = *(const int4*)(src + e);
            int4 dv = *(const int4*)(dst + e);
            s[j*4+0] = sv.x; s[j*4+1] = sv.y; s[j*4+2] = sv.z; s[j*4+3] = sv.w;
            d[j*4+0] = dv.x; d[j*4+1] = dv.y; d[j*4+2] = dv.z; d[j*4+3] = dv.w;
        } else {
            #pragma unroll
            for (int k = 0; k < 4; ++k) {
                int ee = e + k;
                s[j*4+k] = (ee < n_edges) ? src[ee] : -1;
                d[j*4+k] = (ee < n_edges) ? dst[ee] : -1;
            }
        }
    }
    __syncthreads();
    #pragma unroll
    for (int j = 0; j < 8; ++j) {
        if (d[j] >= 0) {
            atomicAdd(&lcnt[d[j] >> BSHIFT], 1);
            if (degmode == 1) atomicAdd(&mcnt[s[j] >> BSHIFT], 1);
            else              atomicAdd(&hs[s[j]], 1);
        }
    }
    __syncthreads();
    int c  = lcnt[t];
    int c2 = mcnt[t];
    int rc  = (c  + 15) & ~15;
    int rc2 = (c2 + 15) & ~15;
    int gr = 0, gr2 = 0;
    if (c  > 0) gr  = atomicAdd(&gcursor[t],  rc);
    if (c2 > 0) gr2 = atomicAdd(&gcursor2[t], rc2);
    int lb  = (c  > 0) ? atomicAdd(&ltot, c)  : 0;
    int lb2 = (c2 > 0) ? atomicAdd(&mtot, c2) : 0;
    lbase[t] = lb;  lcur[t] = lb;
    mbase[t] = lb2; mcur[t] = lb2;
    __syncthreads();
    #pragma unroll
    for (int j = 0; j < 8; ++j) {
        if (d[j] >= 0) {
            int bin = d[j] >> BSHIFT;
            int pos = atomicAdd(&lcur[bin], 1);
            sbuf[pos] = ((unsigned int)d[j] << 16) | (unsigned int)s[j];
            if (degmode == 1) {
                int sbin = s[j] >> BSHIFT;
                int pos2 = atomicAdd(&mcur[sbin], 1);
                sbuf2[pos2] = (unsigned short)s[j];
            }
        }
    }
    lgres[t] = gr; mgres[t] = gr2;
    __syncthreads();
    int m = ltot;
    for (int pos = t; pos < m; pos += 512) {
        unsigned int p = sbuf[pos];
        int bin = (int)(p >> (16 + BSHIFT));
        int gidx = lgres[bin] + (pos - lbase[bin]);
        if (gidx < CAP) {
            unsigned int* gp = (bin == nb - 1) ? gp_last : (gp_main + (size_t)bin * CAP);
            gp[gidx] = p;
        } else {
            int op = atomicAdd(ofl_cnt, 1);
            if (op < ofl_cap) ofl[op] = p;
        }
    }
    int m2 = mtot;
    for (int pos = t; pos < m2; pos += 512) {
        unsigned short v = sbuf2[pos];
        int bin = (int)(v >> BSHIFT);
        int gidx = mgres[bin] + (pos - mbase[bin]);
        if (gidx < CAP2) {
            srcpk[(size_t)bin * CAP2 + gidx] = v;
        } else {
            int op = atomicAdd(ofl2_cnt, 1);
            if (op < ofl2_cap) ofl2[op] = (unsigned int)v;
        }
    }
    for (int i = c; i < rc; ++i) {
        int g = gr + i;
        if (g < CAP) {
            unsigned int* gp = (t == nb - 1) ? gp_last : (gp_main + (size_t)t * CAP);
            gp[g] = SENT;
        }
    }
    for (int i = c2; i < rc2; ++i) {
        int g = gr2 + i;
        if (g < CAP2) srcpk[(size_t)t * CAP2 + g] = 0xFFFFu;
    }
}

// ---- K0+K1 fused (mode 2): partition-first order + EXACT reservation.
// No reservation padding -> regions are dense (only real edges): the ~870K
// scattered 4B dst-sentinels + 870K 2B srcpk-sentinels per launch (R9's
// measured scattered-write poison class) disappear, along with two serial
// tail-write loops per block. Downstream scans need no SENT filtering.
__global__ __launch_bounds__(512) void fused_prep_part_kernel(
    const float* __restrict__ h, const float* __restrict__ W,
    unsigned short* __restrict__ hw, int n_nodes,
    const int* __restrict__ src, const int* __restrict__ dst,
    int* __restrict__ gcursor, int* __restrict__ gcursor2,
    unsigned int* __restrict__ gp_main, unsigned int* __restrict__ gp_last,
    unsigned short* __restrict__ srcpk,
    int* __restrict__ ofl_cnt, unsigned int* __restrict__ ofl, int ofl_cap,
    int* __restrict__ ofl2_cnt, unsigned int* __restrict__ ofl2, int ofl2_cap,
    int nb, int n_edges, int ab, int grid_total) {
    __shared__ int lcnt[NBMAX], ldel[NBMAX];
    __shared__ int mcnt[NBMAX], mdel[NBMAX];
    __shared__ unsigned int sbuf[A_TILE];
    __shared__ unsigned short sbuf2[A_TILE];
    __shared__ int ltot, mtot;
    int t = threadIdx.x;
    int bid = blockIdx.x;
    if (bid < ab) {
        // ---------------- partition role, tile bid ----------------
        int tile = bid * A_TILE;
        lcnt[t] = 0; mcnt[t] = 0;
        if (t == 0) { ltot = 0; mtot = 0; }
        int s[8], d[8];
        int e0 = tile + t * 8;
        #pragma unroll
        for (int j = 0; j < 2; ++j) {
            int e = e0 + j * 4;
            if (e + 3 < n_edges) {
                int4 sv = *(const int4*)(src + e);
                int4 dv = *(const int4*)(dst + e);
                s[j*4+0] = sv.x; s[j*4+1] = sv.y; s[j*4+2] = sv.z; s[j*4+3] = sv.w;
                d[j*4+0] = dv.x; d[j*4+1] = dv.y; d[j*4+2] = dv.z; d[j*4+3] = dv.w;
            } else {
                #pragma unroll
                for (int k = 0; k < 4; ++k) {
                    int ee = e + k;
                    s[j*4+k] = (ee < n_edges) ? src[ee] : -1;
                    d[j*4+k] = (ee < n_edges) ? dst[ee] : -1;
                }
            }
        }
        __syncthreads();
        #pragma unroll
        for (int j = 0; j < 8; ++j) {
            if (d[j] >= 0) {
                atomicAdd(&lcnt[d[j] >> BSHIFT], 1);
                atomicAdd(&mcnt[s[j] >> BSHIFT], 1);
            }
        }
        __syncthreads();
        int c  = lcnt[t];
        int c2 = mcnt[t];
        int gr = 0, gr2 = 0;
        if (c  > 0) gr  = atomicAdd(&gcursor[t],  c);     // EXACT reservation
        if (c2 > 0) gr2 = atomicAdd(&gcursor2[t], c2);
        int lb  = (c  > 0) ? atomicAdd(&ltot, c)  : 0;
        int lb2 = (c2 > 0) ? atomicAdd(&mtot, c2) : 0;
        // reuse lcnt/mcnt as sort cursors; ldel/mdel = LDS->global index shift.
        lcnt[t] = lb;  ldel[t] = gr - lb;
        mcnt[t] = lb2; mdel[t] = gr2 - lb2;
        __syncthreads();
        #pragma unroll
        for (int j = 0; j < 8; ++j) {
            if (d[j] >= 0) {
                int bin = d[j] >> BSHIFT;
                int pos = atomicAdd(&lcnt[bin], 1);
                sbuf[pos] = ((unsigned int)d[j] << 16) | (unsigned int)s[j];
                int sbin = s[j] >> BSHIFT;
                int pos2 = atomicAdd(&mcnt[sbin], 1);
                sbuf2[pos2] = (unsigned short)s[j];
            }
        }
        __syncthreads();
        int m = ltot;
        for (int pos = t; pos < m; pos += 512) {
            unsigned int p = sbuf[pos];
            int bin = (int)(p >> (16 + BSHIFT));
            int gidx = pos + ldel[bin];
            if (gidx < CAP) {
                unsigned int* gp = (bin == nb - 1) ? gp_last : (gp_main + (size_t)bin * CAP);
                gp[gidx] = p;
            } else {
                int op = atomicAdd(ofl_cnt, 1);
                if (op < ofl_cap) ofl[op] = p;
            }
        }
        int m2 = mtot;
        for (int pos = t; pos < m2; pos += 512) {
            unsigned short v = sbuf2[pos];
            int bin = (int)(v >> BSHIFT);
            int gidx = pos + mdel[bin];
            if (gidx < CAP2) {
                srcpk[(size_t)bin * CAP2 + gidx] = v;
            } else {
                int op = atomicAdd(ofl2_cnt, 1);
                if (op < ofl2_cap) ofl2[op] = (unsigned int)v;
            }
        }
        // no sentinel padding: regions are dense
    } else {
        // ---------------- prep role, prep_idx = bid - ab ----------------
        int prep_idx = bid - ab;
        int gid = prep_idx * 512 + t;
        int S = n_nodes + ZPAD;
        if (gid < 16) {
            ((unsigned int*)hw)[(size_t)n_nodes * 16 + gid] = 0u;
        } else if (gid < 32) {
            ((unsigned int*)hw)[(size_t)S * 16 + (size_t)n_nodes * 16 + (gid - 16)] = 0u;
        }
        int lane = t & 63;
        int wv = __builtin_amdgcn_readfirstlane(t >> 6);
        float wcol[D];
        #pragma unroll
        for (int k = 0; k < D; ++k) wcol[k] = W[k * D + lane];
        unsigned short* half0 = hw;
        unsigned short* half1 = hw + (size_t)S * 32;
        int row0 = (prep_idx * 8 + wv) * 4;
        if (row0 >= n_nodes) return;
        const float4* hr = (const float4*)(h + (size_t)row0 * D);   // wave-uniform
        float a0a = 0.f, a0b = 0.f, a1a = 0.f, a1b = 0.f;
        float a2a = 0.f, a2b = 0.f, a3a = 0.f, a3b = 0.f;
        if (row0 + 4 <= n_nodes) {
            #pragma unroll
            for (int k4 = 0; k4 < 16; ++k4) {
                float4 v0 = hr[k4];
                float4 v1 = hr[16 + k4];
                float4 v2 = hr[32 + k4];
                float4 v3 = hr[48 + k4];
                a0a = fmaf(v0.x, wcol[4*k4+0], a0a); a0b = fmaf(v0.y, wcol[4*k4+1], a0b);
                a0a = fmaf(v0.z, wcol[4*k4+2], a0a); a0b = fmaf(v0.w, wcol[4*k4+3], a0b);
                a1a = fmaf(v1.x, wcol[4*k4+0], a1a); a1b = fmaf(v1.y, wcol[4*k4+1], a1b);
                a1a = fmaf(v1.z, wcol[4*k4+2], a1a); a1b = fmaf(v1.w, wcol[4*k4+3], a1b);
                a2a = fmaf(v2.x, wcol[4*k4+0], a2a); a2b = fmaf(v2.y, wcol[4*k4+1], a2b);
                a2a = fmaf(v2.z, wcol[4*k4+2], a2a); a2b = fmaf(v2.w, wcol[4*k4+3], a2b);
                a3a = fmaf(v3.x, wcol[4*k4+0], a3a); a3b = fmaf(v3.y, wcol[4*k4+1], a3b);
                a3a = fmaf(v3.z, wcol[4*k4+2], a3a); a3b = fmaf(v3.w, wcol[4*k4+3], a3b);
            }
            unsigned short r0 = f2bf(a0a + a0b);
            unsigned short r1 = f2bf(a1a + a1b);
            unsigned short r2 = f2bf(a2a + a2b);
            unsigned short r3 = f2bf(a3a + a3b);
            if (lane < 32) {
                half0[(size_t)(row0 + 0) * 32 + lane] = r0;
                half0[(size_t)(row0 + 1) * 32 + lane] = r1;
                half0[(size_t)(row0 + 2) * 32 + lane] = r2;
                half0[(size_t)(row0 + 3) * 32 + lane] = r3;
            } else {
                half1[(size_t)(row0 + 0) * 32 + lane - 32] = r0;
                half1[(size_t)(row0 + 1) * 32 + lane - 32] = r1;
                half1[(size_t)(row0 + 2) * 32 + lane - 32] = r2;
                half1[(size_t)(row0 + 3) * 32 + lane - 32] = r3;
            }
        } else {
            for (int r = 0; r < 4; ++r) {
                int row = row0 + r;
                if (row >= n_nodes) break;
                float aa = 0.f, ab2 = 0.f;
                #pragma unroll
                for (int k4 = 0; k4 < 16; ++k4) {
                    float4 v = hr[r * 16 + k4];
                    aa = fmaf(v.x, wcol[4*k4+0], aa); ab2 = fmaf(v.y, wcol[4*k4+1], ab2);
                    aa = fmaf(v.z, wcol[4*k4+2], aa); ab2 = fmaf(v.w, wcol[4*k4+3], ab2);
                }
                unsigned short val = f2bf(aa + ab2);
                if (lane < 32) half0[(size_t)row * 32 + lane] = val;
                else           half1[(size_t)row * 32 + lane - 32] = val;
            }
        }
    }
}

// ---- K1b (mode 1): out-degree from srcpk regions ----
__global__ __launch_bounds__(512) void deg_from_srcpk(
    const int* __restrict__ gcursor2, const unsigned short* __restrict__ srcpk,
    const int* __restrict__ ofl2_cnt_p, const unsigned int* __restrict__ ofl2, int ofl2_cap,
    int* __restrict__ deg, int nb, int n_nodes) {
    __shared__ int hist[NPB];
    int t = threadIdx.x;
    int b = blockIdx.x;
    if (t < NPB) hist[t] = 0;
    __syncthreads();
    int cnt2 = gcursor2[b]; if (cnt2 > CAP2) cnt2 = CAP2;
    const unsigned short* r2 = srcpk + (size_t)b * CAP2;
    for (int i = t; i < cnt2; i += 512) {
        unsigned short v = r2[i];
        if (v != 0xFFFFu) atomicAdd(&hist[v & (NPB - 1)], 1);
    }
    int n2 = *ofl2_cnt_p; if (n2 < 0) n2 = 0; if (n2 > ofl2_cap) n2 = ofl2_cap;
    for (int i = t; i < n2; i += 512) {
        unsigned int v = ofl2[i];
        if ((int)(v >> BSHIFT) == b) atomicAdd(&hist[v & (NPB - 1)], 1);
    }
    __syncthreads();
    if (t < NPB) {
        int node = b * NPB + t;
        if (node < n_nodes) deg[node] = hist[t];
    }
}

// ---- K1b+K1c fused (mode 2): deg hist + node-sorted padded CSR, one block/bucket.
// Regions are dense (exact reservation) — every entry is a real edge.
__global__ __launch_bounds__(512) void fused_deg_csr_kernel(
    const int* __restrict__ gcursor2, const unsigned short* __restrict__ srcpk,
    const int* __restrict__ ofl2_cnt_p, const unsigned int* __restrict__ ofl2, int ofl2_cap,
    int* __restrict__ deg,
    const int* __restrict__ gcursor,
    const unsigned int* gp_main, const unsigned int* gp_last,
    const int* __restrict__ ofl_cnt_p, const unsigned int* __restrict__ ofl, int ofl_cap,
    unsigned short* __restrict__ gcsr,
    int* __restrict__ nodeoff, int* __restrict__ nodecnt,
    int nb, int n_nodes) {
    __shared__ int hist[NPB];
    __shared__ int lcnt[NPB], loff[NPB], lcur[NPB], lpc[NPB];
    __shared__ unsigned short csr[CAP2];
    int t = threadIdx.x;
    int lane = t & 63;
    int wv = t >> 6;
    int b = blockIdx.x;

    if (t < NPB) { hist[t] = 0; lcnt[t] = 0; }
    __syncthreads();

    int cnt2 = gcursor2[b]; if (cnt2 > CAP2) cnt2 = CAP2;
    const unsigned short* r2 = srcpk + (size_t)b * CAP2;
    for (int i = t; i < cnt2; i += 512) {
        unsigned short v = r2[i];
        atomicAdd(&hist[v & (NPB - 1)], 1);
    }
    int n2 = *ofl2_cnt_p; if (n2 < 0) n2 = 0; if (n2 > ofl2_cap) n2 = ofl2_cap;
    for (int i = t; i < n2; i += 512) {
        unsigned int v = ofl2[i];
        if ((int)(v >> BSHIFT) == b) atomicAdd(&hist[v & (NPB - 1)], 1);
    }

    const unsigned int* region = (b == nb - 1) ? gp_last : (gp_main + (size_t)b * CAP);
    int cnt = gcursor[b]; if (cnt > CAP) cnt = CAP;
    int ofn = *ofl_cnt_p; if (ofn < 0) ofn = 0; if (ofn > ofl_cap) ofn = ofl_cap;
    unsigned int ep[EPT];
    #pragma unroll
    for (int u = 0; u < EPT; ++u) {
        int i = t + u * 512;
        ep[u] = (i < cnt) ? region[i] : SENT;
    }
    #pragma unroll
    for (int u = 0; u < EPT; ++u) {
        if (ep[u] != SENT)
            atomicAdd(&lcnt[(ep[u] >> 16) & (NPB - 1)], 1);
    }
    for (int i = t; i < ofn; i += 512) {
        unsigned int p = ofl[i];
        if ((int)(p >> (16 + BSHIFT)) == b)
            atomicAdd(&lcnt[(p >> 16) & (NPB - 1)], 1);
    }
    __syncthreads();

    if (t < NPB) {
        int node = b * NPB + t;
        if (node < n_nodes) deg[node] = hist[t];
    }

    if (wv == 0) {
        int c0 = lcnt[lane];
        int c1 = lcnt[lane + 64];
        int p0 = (c0 + 15) & ~15;
        int p1 = (c1 + 15) & ~15;
        int sm = p0 + p1;
        int x = sm;
        #pragma unroll
        for (int o = 1; o < 64; o <<= 1) {
            int y = __shfl_up(x, o);
            if (lane >= o) x += y;
        }
        int base = x - sm;
        loff[lane] = base;            lcur[lane] = base;            lpc[lane] = p0;
        loff[lane + 64] = base + p0;  lcur[lane + 64] = base + p0;  lpc[lane + 64] = p1;
    }
    __syncthreads();
    if (t < NPB) {
        nodeoff[(size_t)b * NPB + t] = loff[t];
        nodecnt[(size_t)b * NPB + t] = lpc[t];
    }
    #pragma unroll
    for (int u = 0; u < EPT; ++u) {
        if (ep[u] != SENT) {
            int nl = (int)((ep[u] >> 16) & (NPB - 1));
            int pos = atomicAdd(&lcur[nl], 1);
            if (pos < CAP2) csr[pos] = (unsigned short)(ep[u] & 0xFFFFu);
        }
    }
    for (int i = t; i < ofn; i += 512) {
        unsigned int p = ofl[i];
        if ((int)(p >> (16 + BSHIFT)) == b) {
            int nl = (int)((p >> 16) & (NPB - 1));
            int pos = atomicAdd(&lcur[nl], 1);
            if (pos < CAP2) csr[pos] = (unsigned short)(p & 0xFFFFu);
        }
    }
    __syncthreads();
    if (t < NPB) {                                 // zero-row padding fill
        int i0 = loff[t] + lcnt[t];
        int i1 = loff[t] + lpc[t];
        for (int i = i0; i < i1; ++i)
            if (i < CAP2) csr[i] = (unsigned short)n_nodes;
    }
    __syncthreads();
    int tot = loff[NPB - 1] + lpc[NPB - 1];
    if (tot > CAP2) tot = CAP2;
    unsigned int* gc = (unsigned int*)(gcsr + (size_t)b * CAP2);
    const unsigned int* lc4 = (const unsigned int*)csr;
    for (int i = t; i < (tot + 1) / 2; i += 512) gc[i] = lc4[i];
}

// ---- K2 (mode 2): predicate-free CSR gather; BOTH passes in one dispatch ----
__global__ __launch_bounds__(512, 2) void gather_csr_kernel(
    const unsigned short* __restrict__ hw, const float* __restrict__ bias,
    const int* __restrict__ degarr,
    const unsigned short* __restrict__ gcsr,
    const int* __restrict__ nodeoff, const int* __restrict__ nodecnt,
    int nb, float* __restrict__ out, int n_nodes) {
    __shared__ unsigned short csr[CAP2];
    __shared__ int lo[32], lc[32];
    int t = threadIdx.x;
    int lane = t & 63;
    int wv = t >> 6;
    int g = lane >> 3;
    int l8 = lane & 7;
    int blk = blockIdx.x;
    int half_n = nb * 4;
    int pass = (blk >= half_n) ? 1 : 0;
    int r = blk - pass * half_n;
    int b = r >> 2;
    int hh = r & 3;
    int S = n_nodes + ZPAD;

    int idx0 = b * NPB + hh * 32;
    int base = nodeoff[idx0];
    int end  = nodeoff[idx0 + 31] + nodecnt[idx0 + 31];
    if (base > CAP2) base = CAP2;
    if (end > CAP2) end = CAP2;
    int len = end - base; if (len < 0) len = 0;
    const unsigned int* gc = (const unsigned int*)(gcsr + (size_t)b * CAP2 + base);
    unsigned int* lc4 = (unsigned int*)csr;
    for (int i = t; i < (len + 1) / 2; i += 512) lc4[i] = gc[i];
    if (t < 32) {
        int idx = idx0 + t;
        int off = nodeoff[idx] - base;
        int pc = nodecnt[idx];
        if (off < 0) off = 0;
        if (off > len) off = len;
        if (pc > len - off) pc = (len - off) & ~15;
        if (pc < 0) pc = 0;
        lo[t] = off; lc[t] = pc;
    }
    __syncthreads();

    int pair = wv * 4 + (g >> 1);
    int off = lo[pair];
    int pc = lc[pair];
    float acc[4];
    acc[0] = acc[1] = acc[2] = acc[3] = 0.f;

    const uint2* hwh = (const uint2*)(hw + (size_t)pass * S * 32);
    for (int j = (g & 1) * 8; j < pc; j += 16) {
        uint2 v[8];
        #pragma unroll
        for (int u = 0; u < 8; ++u) {
            int ss = (int)csr[off + j + u];
            v[u] = hwh[(unsigned)(ss * 8 + l8)];
        }
        #pragma unroll
        for (int u = 0; u < 8; ++u) {
            acc[0] += bflo(v[u].x); acc[1] += bfhi(v[u].x);
            acc[2] += bflo(v[u].y); acc[3] += bfhi(v[u].y);
        }
    }

    #pragma unroll
    for (int q = 0; q < 4; ++q)
        acc[q] += __shfl_xor(acc[q], 8);

    if (!(g & 1)) {
        int node = b * NPB + hh * 32 + pair;
        if (node < n_nodes) {
            float4 bv = ((const float4*)bias)[pass * 8 + l8];
            float nrm = rsqrtf((float)degarr[node]);
            float4 rr;
            rr.x = fmaxf(fmaf(acc[0], nrm, bv.x), 0.f);
            rr.y = fmaxf(fmaf(acc[1], nrm, bv.y), 0.f);
            rr.z = fmaxf(fmaf(acc[2], nrm, bv.z), 0.f);
            rr.w = fmaxf(fmaf(acc[3], nrm, bv.w), 0.f);
            ((float4*)out)[(size_t)node * 16 + pass * 8 + l8] = rr;
        }
    }
}

// ---- old combined gather (modes 0/1 only; padded regions with SENT) ----
template<int NLOC>
__global__ __launch_bounds__(512, 2) void bucket_gather_t(
    const unsigned short* __restrict__ hw, const float* __restrict__ bias,
    const int* __restrict__ gcursor, const int* __restrict__ degarr,
    const unsigned int* gp_main, const unsigned int* gp_last,  // may alias out
    const int* __restrict__ ofl_cnt_p, const unsigned int* __restrict__ ofl, int ofl_cap,
    int nb, float* out, int n_nodes) {
    constexpr int SPB = NPB / NLOC;
    __shared__ int lcnt[NLOC];
    __shared__ int loff[NLOC];
    __shared__ int lcur[NLOC];
    __shared__ unsigned short csr[ECAP];
    int t = threadIdx.x;
    int lane = t & 63;
    int wv = t >> 6;
    int g = lane >> 3;
    int l8 = lane & 7;
    int blk = blockIdx.x;
    int b = blk / SPB;
    int hh = blk % SPB;
    int S = n_nodes + ZPAD;
    const unsigned int* region = (b == nb - 1) ? gp_last : (gp_main + (size_t)b * CAP);
    int cnt = gcursor[b]; if (cnt > CAP) cnt = CAP;
    int ofn = *ofl_cnt_p; if (ofn < 0) ofn = 0; if (ofn > ofl_cap) ofn = ofl_cap;

    constexpr int KN = NLOC / 64;
    float acc[KN][2][4];
    #pragma unroll
    for (int k = 0; k < KN; ++k)
        #pragma unroll
        for (int p = 0; p < 2; ++p)
            #pragma unroll
            for (int q = 0; q < 4; ++q) acc[k][p][q] = 0.f;

    int nch = 1 + ((ofn > 0) ? (ofn + ECAP - 1) / ECAP : 0);
    for (int ch = 0; ch < nch; ++ch) {
        const unsigned int* sp; int m;
        if (ch == 0) { sp = region; m = cnt; }
        else {
            sp = ofl + (size_t)(ch - 1) * ECAP;
            m = ofn - (ch - 1) * ECAP; if (m > ECAP) m = ECAP;
        }
        if (t < NLOC) lcnt[t] = 0;
        __syncthreads();
        unsigned int ep[EPT];
        #pragma unroll
        for (int u = 0; u < EPT; ++u) {
            int i = t + u * 512;
            ep[u] = (i < m) ? sp[i] : SENT;
        }
        #pragma unroll
        for (int u = 0; u < EPT; ++u) {
            if (ep[u] != SENT) {
                int pb = (int)(ep[u] >> (16 + BSHIFT));
                int nl_r = (int)((ep[u] >> 16) & (NPB - 1));
                if (pb != b || (SPB == 2 && ((nl_r >> 6) != hh))) ep[u] = SENT;
            }
        }
        #pragma unroll
        for (int u = 0; u < EPT; ++u)
            if (ep[u] != SENT)
                atomicAdd(&lcnt[(ep[u] >> 16) & (NLOC - 1)], 1);
        __syncthreads();
        if (wv == 0) {
            if (NLOC == 128) {
                int v0 = lcnt[lane];
                int v1 = lcnt[lane + 64];
                int sm = v0 + v1;
                int x = sm;
                #pragma unroll
                for (int o = 1; o < 64; o <<= 1) {
                    int y = __shfl_up(x, o);
                    if (lane >= o) x += y;
                }
                int base = x - sm;
                loff[lane] = base;            lcur[lane] = base;
                loff[lane + 64] = base + v0;  lcur[lane + 64] = base + v0;
            } else {
                int v = lcnt[lane];
                int x = v;
                #pragma unroll
                for (int o = 1; o < 64; o <<= 1) {
                    int y = __shfl_up(x, o);
                    if (lane >= o) x += y;
                }
                loff[lane] = x - v;
                lcur[lane] = x - v;
            }
        }
        __syncthreads();
        #pragma unroll
        for (int u = 0; u < EPT; ++u)
            if (ep[u] != SENT) {
                int nl = (int)((ep[u] >> 16) & (NLOC - 1));
                int pos = atomicAdd(&lcur[nl], 1);
                csr[pos] = (unsigned short)(ep[u] & 0xFFFFu);
            }
        __syncthreads();
        #pragma unroll
        for (int p = 0; p < 2; ++p) {
            const uint2* hwh = (const uint2*)(hw + (size_t)p * S * 32);
            #pragma unroll
            for (int k = 0; k < KN; ++k) {
                int nl = k * 64 + wv * 8 + g;
                int off = loff[nl];
                int c = lcnt[nl];
                for (int j = 0; j < c; j += 8) {
                    uint2 v[8];
                    bool ok[8];
                    #pragma unroll
                    for (int u = 0; u < 8; ++u) {
                        int idx = j + u;
                        ok[u] = idx < c;
                        int ss = (int)csr[off + (ok[u] ? idx : 0)];
                        v[u] = ok[u] ? hwh[(size_t)ss * 8 + l8] : make_uint2(0, 0);
                    }
                    #pragma unroll
                    for (int u = 0; u < 8; ++u) {
                        acc[k][p][0] += bflo(v[u].x); acc[k][p][1] += bfhi(v[u].x);
                        acc[k][p][2] += bflo(v[u].y); acc[k][p][3] += bfhi(v[u].y);
                    }
                }
            }
        }
        __syncthreads();
    }

    float4 bv0 = ((const float4*)bias)[l8];
    float4 bv1 = ((const float4*)bias)[8 + l8];
    int node0 = b * NPB + hh * 64;
    #pragma unroll
    for (int k = 0; k < KN; ++k) {
        int nl = k * 64 + wv * 8 + g;
        int node = node0 + nl;
        if (node >= n_nodes) continue;
        float nrm = rsqrtf((float)degarr[node]);
        float4 r0, r1;
        r0.x = fmaxf(fmaf(acc[k][0][0], nrm, bv0.x), 0.f);
        r0.y = fmaxf(fmaf(acc[k][0][1], nrm, bv0.y), 0.f);
        r0.z = fmaxf(fmaf(acc[k][0][2], nrm, bv0.z), 0.f);
        r0.w = fmaxf(fmaf(acc[k][0][3], nrm, bv0.w), 0.f);
        r1.x = fmaxf(fmaf(acc[k][1][0], nrm, bv1.x), 0.f);
        r1.y = fmaxf(fmaf(acc[k][1][1], nrm, bv1.y), 0.f);
        r1.z = fmaxf(fmaf(acc[k][1][2], nrm, bv1.z), 0.f);
        r1.w = fmaxf(fmaf(acc[k][1][3], nrm, bv1.w), 0.f);
        ((float4*)out)[(size_t)node * 16 + l8]     = r0;
        ((float4*)out)[(size_t)node * 16 + 8 + l8] = r1;
    }
}

// ---------------- fallback atomic path (if ws too small / shape odd) ----------------

__global__ void deg_kernel(const int* __restrict__ src, float* __restrict__ deg, int n_edges) {
    int e = blockIdx.x * blockDim.x + threadIdx.x;
    if (e < n_edges) atomicAdd(&deg[src[e]], 1.0f);
}

__global__ void scatter_kernel(const float* __restrict__ h, const int* __restrict__ src,
                               const int* __restrict__ dst, float* __restrict__ agg,
                               int n_edges) {
    long long tid = (long long)blockIdx.x * blockDim.x + threadIdx.x;
    int e = (int)(tid >> 6);
    int f = (int)(tid & 63);
    if (e < n_edges) {
        atomicAdd(&agg[(long long)dst[e] * D + f], h[(long long)src[e] * D + f]);
    }
}

__global__ void transform_kernel(float* __restrict__ agg_out, const float* __restrict__ W,
                                 const float* __restrict__ bias, const float* __restrict__ deg,
                                 int n_nodes) {
    __shared__ float w_lds[D][D];
    __shared__ float a_lds[4][D];
    __shared__ float b_lds[D];
    int t = threadIdx.x;
    for (int i = t; i < D * D; i += 256) w_lds[i >> 6][i & 63] = W[i];
    if (t < D) b_lds[t] = bias[t];
    int rl = t >> 6, col = t & 63;
    int row = blockIdx.x * 4 + rl;
    if (row < n_nodes) a_lds[rl][col] = agg_out[(long long)row * D + col];
    __syncthreads();
    if (row < n_nodes) {
        float sum = 0.f;
        #pragma unroll
        for (int k = 0; k < D; ++k) sum = fmaf(a_lds[rl][k], w_lds[k][col], sum);
        float v = fmaf(sum, rsqrtf(deg[row]), b_lds[col]);
        agg_out[(long long)row * D + col] = fmaxf(v, 0.f);
    }
}

extern "C" void kernel_launch(void* const* d_in, const int* in_sizes, int n_in,
                              void* d_out, int out_size, void* d_ws, size_t ws_size,
                              hipStream_t stream) {
    const float* h    = (const float*)d_in[0];
    const float* W    = (const float*)d_in[1];
    const float* bias = (const float*)d_in[2];
    const int*   src  = (const int*)d_in[3];
    const int*   dst  = (const int*)d_in[4];
    float* out = (float*)d_out;

    int n_nodes = in_sizes[0] / D;
    int n_edges = in_sizes[3];
    int nb = (n_nodes + NPB - 1) / NPB;

    bool shape_ok = (nb <= NBMAX - 1) && (n_nodes <= 65408) && (n_nodes % 2 == 0) &&
                    ((size_t)out_size == (size_t)n_nodes * D);
    size_t head = 2 * (size_t)NBMAX + 2;
    size_t hw_ints = (size_t)(n_nodes + ZPAD) * 32;   // two halves, (n+ZPAD) rows x 32 bf16
    // mode 2: regions in ws, csr path, srcpk deg, nodeoff/cnt
    size_t gp2   = (head + 3) & ~(size_t)3;
    size_t hw2s  = gp2 + (size_t)nb * CAP;
    size_t spk2  = hw2s + hw_ints;
    size_t csr2  = spk2 + (size_t)nb * (CAP2 / 2);    // separate csr store
    size_t ofl2s = csr2 + (size_t)nb * (CAP2 / 2);
    size_t of22s = ofl2s + 16384;
    size_t deg2  = of22s + 8192;
    size_t noff2 = deg2 + n_nodes;
    size_t ncnt2 = noff2 + (size_t)nb * NPB;
    size_t need2 = (ncnt2 + (size_t)nb * NPB) * 4;
    // mode 1: regions alias d_out
    size_t gpl1 = (head + 3) & ~(size_t)3;
    size_t hw1  = gpl1 + CAP;
    size_t spk1 = hw1 + hw_ints;
    size_t ofl1 = spk1 + (size_t)nb * (CAP2 / 2);
    size_t of21 = ofl1 + 16384;
    size_t deg1 = of21 + 8192;
    size_t need1 = (deg1 + n_nodes) * 4;
    // mode 0: legacy global hs, regions alias d_out
    size_t hs0  = head;
    size_t gpl0 = (hs0 + n_nodes + 3) & ~(size_t)3;
    size_t hw0  = gpl0 + CAP;
    size_t ofl0 = hw0 + hw_ints;
    size_t need0 = (ofl0 + 16384) * 4;

    if (shape_ok && ws_size >= need0) {
        int mode = (ws_size >= need2) ? 2 : ((ws_size >= need1) ? 1 : 0);
        int* wsI = (int*)d_ws;
        int* gcursor  = wsI;
        int* gcursor2 = wsI + NBMAX;
        int* ofl_cnt  = wsI + 2 * NBMAX;
        int* ofl2_cnt = wsI + 2 * NBMAX + 1;
        unsigned int* gp_main; unsigned int* gp_last;
        unsigned short* hw; unsigned short* srcpk; unsigned short* gcsrp = 0;
        unsigned int* ofl; unsigned int* ofl2;
        int* degp; int* noffp = 0; int* ncntp = 0; int* hs;
        if (mode == 2) {
            gp_main = (unsigned int*)(wsI + gp2);
            gp_last = gp_main + (size_t)(nb - 1) * CAP;
            hw      = (unsigned short*)(wsI + hw2s);
            srcpk   = (unsigned short*)(wsI + spk2);
            gcsrp   = (unsigned short*)(wsI + csr2);
            ofl     = (unsigned int*)(wsI + ofl2s);
            ofl2    = (unsigned int*)(wsI + of22s);
            degp    = wsI + deg2;
            noffp   = wsI + noff2;
            ncntp   = wsI + ncnt2;
            hs      = gcursor;                   // dummy
        } else if (mode == 1) {
            gp_main = (unsigned int*)d_out;
            gp_last = (unsigned int*)(wsI + gpl1);
            hw      = (unsigned short*)(wsI + hw1);
            srcpk   = (unsigned short*)(wsI + spk1);
            ofl     = (unsigned int*)(wsI + ofl1);
            ofl2    = (unsigned int*)(wsI + of21);
            degp    = wsI + deg1;
            hs      = gcursor;                   // dummy (degmode==1)
        } else {
            gp_main = (unsigned int*)d_out;
            gp_last = (unsigned int*)(wsI + gpl0);
            hw      = (unsigned short*)(wsI + hw0);
            srcpk   = (unsigned short*)(wsI + gpl0);   // unused
            ofl     = (unsigned int*)(wsI + ofl0);
            ofl2    = (unsigned int*)(wsI + ofl0);     // unused
            degp    = wsI + hs0;
            hs      = degp;
        }
        int ofl_cap = 16384, ofl2_cap = (mode >= 1) ? 8192 : 0;

        int pb = (n_nodes + 31) / 32;            // 4 rows/wave x 8 waves
        int ab = (n_edges + A_TILE - 1) / A_TILE;

        if (mode == 2) {
            zero_head_kernel<<<(int)((head + 511) / 512), 512, 0, stream>>>(wsI, (int)head);
            int grid_total = pb + ab;
            fused_prep_part_kernel<<<grid_total, 512, 0, stream>>>(
                h, W, hw, n_nodes, src, dst, gcursor, gcursor2,
                gp_main, gp_last, srcpk,
                ofl_cnt, ofl, ofl_cap, ofl2_cnt, ofl2, ofl2_cap,
                nb, n_edges, ab, grid_total);
            fused_deg_csr_kernel<<<nb, 512, 0, stream>>>(
                gcursor2, srcpk, ofl2_cnt, ofl2, ofl2_cap, degp,
                gcursor, gp_main, gp_last, ofl_cnt, ofl, ofl_cap,
                gcsrp, noffp, ncntp, nb, n_nodes);
            gather_csr_kernel<<<nb * 8, 512, 0, stream>>>(
                hw, bias, degp, gcsrp, noffp, ncntp, nb, out, n_nodes);
        } else {
            int degmode = (mode >= 1) ? 1 : 0;
            int zc1 = (int)head;
            int zc2 = (mode >= 1) ? 0 : n_nodes;
            int* z2p = (mode >= 1) ? wsI : degp;
            prep_hw_kernel<<<pb, 512, 0, stream>>>(h, W, hw, wsI, zc1, z2p, zc2, n_nodes);
            partition_kernel<<<ab, 512, 0, stream>>>(src, dst, hs, gcursor, gcursor2,
                                                     gp_main, gp_last, srcpk,
                                                     ofl_cnt, ofl, ofl_cap,
                                                     ofl2_cnt, ofl2, ofl2_cap,
                                                     nb, n_edges, degmode);
            if (mode >= 1)
                deg_from_srcpk<<<nb, 512, 0, stream>>>(gcursor2, srcpk, ofl2_cnt, ofl2,
                                                       ofl2_cap, degp, nb, n_nodes);
            bucket_gather_t<128><<<nb, 512, 0, stream>>>(
                hw, bias, gcursor, degp, gp_main, gp_last,
                ofl_cnt, ofl, ofl_cap, nb, out, n_nodes);
        }
    } else {
        float* deg = (float*)d_ws;
        hipMemsetAsync(out, 0, (size_t)n_nodes * D * sizeof(float), stream);
        hipMemsetAsync(deg, 0, (size_t)n_nodes * sizeof(float), stream);
        int eb = (n_edges + 255) / 256;
        deg_kernel<<<eb, 256, 0, stream>>>(src, deg, n_edges);
        long long total = (long long)n_edges * D;
        scatter_kernel<<<(int)((total + 255) / 256), 256, 0, stream>>>(h, src, dst, out, n_edges);
        transform_kernel<<<(n_nodes + 3) / 4, 256, 0, stream>>>(out, W, bias, deg, n_nodes);
    }
}

// Round 14
// 77.921 us; speedup vs baseline: 1.2750x; 1.0352x over previous
//
#include <hip/hip_runtime.h>

#define D 64
#define BSHIFT 7
#define NPB 128              // nodes per partition bucket (region granularity)
#define NBMAX 512            // max 128-node buckets
#define CAP 8192             // u32 dst-packed slots per bucket region
#define CAP2 8192            // u16 csr slots per bucket
#define A_TILE 4096          // edges per partition block (legacy modes 0/1)
#define PTILE 8192           // edges per fused partition block (512 thr x 16)
#define ECAP CAP
#define EPT (ECAP / 512)     // 16 edges/thread/chunk
#define ZPAD 2               // extra hw rows (zero row at index n_nodes)
#define SENT 0xFFFFFFFFu

__device__ __forceinline__ unsigned short f2bf(float f) {
    unsigned int u = __float_as_uint(f);
    u += 0x7FFFu + ((u >> 16) & 1u);     // RNE
    return (unsigned short)(u >> 16);
}
__device__ __forceinline__ float bflo(unsigned int w) {
    return __uint_as_float(w << 16);
}
__device__ __forceinline__ float bfhi(unsigned int w) {
    return __uint_as_float(w & 0xFFFF0000u);
}

// ---- K-1: zero counter head (must precede fused prep+partition) ----
__global__ __launch_bounds__(512) void zero_head_kernel(int* __restrict__ z, int n) {
    int i = blockIdx.x * 512 + threadIdx.x;
    if (i < n) z[i] = 0;
}

// ---- K0 (modes 0/1): zero counter ranges + hW = h @ W, bf16 two halves ----
__global__ __launch_bounds__(512) void prep_hw_kernel(
    const float* __restrict__ h, const float* __restrict__ W,
    unsigned short* __restrict__ hw,
    int* __restrict__ z1, int zc1, int* __restrict__ z2, int zc2,
    int n_nodes) {
    int t = threadIdx.x;
    int gid = blockIdx.x * 512 + t;
    for (int i = gid; i < zc1; i += gridDim.x * 512) z1[i] = 0;
    for (int i = gid; i < zc2; i += gridDim.x * 512) z2[i] = 0;
    int S = n_nodes + ZPAD;
    if (gid < 16) {
        ((unsigned int*)hw)[(size_t)n_nodes * 16 + gid] = 0u;
    } else if (gid < 32) {
        ((unsigned int*)hw)[(size_t)S * 16 + (size_t)n_nodes * 16 + (gid - 16)] = 0u;
    }
    int lane = t & 63;
    int wv = __builtin_amdgcn_readfirstlane(t >> 6);
    float wcol[D];
    #pragma unroll
    for (int k = 0; k < D; ++k) wcol[k] = W[k * D + lane];
    unsigned short* half0 = hw;
    unsigned short* half1 = hw + (size_t)S * 32;
    int row0 = (blockIdx.x * 8 + wv) * 4;
    if (row0 >= n_nodes) return;
    const float4* hr = (const float4*)(h + (size_t)row0 * D);   // wave-uniform
    float a0a = 0.f, a0b = 0.f, a1a = 0.f, a1b = 0.f;
    float a2a = 0.f, a2b = 0.f, a3a = 0.f, a3b = 0.f;
    if (row0 + 4 <= n_nodes) {
        #pragma unroll
        for (int k4 = 0; k4 < 16; ++k4) {
            float4 v0 = hr[k4];
            float4 v1 = hr[16 + k4];
            float4 v2 = hr[32 + k4];
            float4 v3 = hr[48 + k4];
            a0a = fmaf(v0.x, wcol[4*k4+0], a0a); a0b = fmaf(v0.y, wcol[4*k4+1], a0b);
            a0a = fmaf(v0.z, wcol[4*k4+2], a0a); a0b = fmaf(v0.w, wcol[4*k4+3], a0b);
            a1a = fmaf(v1.x, wcol[4*k4+0], a1a); a1b = fmaf(v1.y, wcol[4*k4+1], a1b);
            a1a = fmaf(v1.z, wcol[4*k4+2], a1a); a1b = fmaf(v1.w, wcol[4*k4+3], a1b);
            a2a = fmaf(v2.x, wcol[4*k4+0], a2a); a2b = fmaf(v2.y, wcol[4*k4+1], a2b);
            a2a = fmaf(v2.z, wcol[4*k4+2], a2a); a2b = fmaf(v2.w, wcol[4*k4+3], a2b);
            a3a = fmaf(v3.x, wcol[4*k4+0], a3a); a3b = fmaf(v3.y, wcol[4*k4+1], a3b);
            a3a = fmaf(v3.z, wcol[4*k4+2], a3a); a3b = fmaf(v3.w, wcol[4*k4+3], a3b);
        }
        unsigned short r0 = f2bf(a0a + a0b);
        unsigned short r1 = f2bf(a1a + a1b);
        unsigned short r2 = f2bf(a2a + a2b);
        unsigned short r3 = f2bf(a3a + a3b);
        if (lane < 32) {
            half0[(size_t)(row0 + 0) * 32 + lane] = r0;
            half0[(size_t)(row0 + 1) * 32 + lane] = r1;
            half0[(size_t)(row0 + 2) * 32 + lane] = r2;
            half0[(size_t)(row0 + 3) * 32 + lane] = r3;
        } else {
            half1[(size_t)(row0 + 0) * 32 + lane - 32] = r0;
            half1[(size_t)(row0 + 1) * 32 + lane - 32] = r1;
            half1[(size_t)(row0 + 2) * 32 + lane - 32] = r2;
            half1[(size_t)(row0 + 3) * 32 + lane - 32] = r3;
        }
    } else {
        for (int r = 0; r < 4; ++r) {
            int row = row0 + r;
            if (row >= n_nodes) break;
            float aa = 0.f, ab = 0.f;
            #pragma unroll
            for (int k4 = 0; k4 < 16; ++k4) {
                float4 v = hr[r * 16 + k4];
                aa = fmaf(v.x, wcol[4*k4+0], aa); ab = fmaf(v.y, wcol[4*k4+1], ab);
                aa = fmaf(v.z, wcol[4*k4+2], aa); ab = fmaf(v.w, wcol[4*k4+3], ab);
            }
            unsigned short val = f2bf(aa + ab);
            if (lane < 32) half0[(size_t)row * 32 + lane] = val;
            else           half1[(size_t)row * 32 + lane - 32] = val;
        }
    }
}

// ---- K1 (modes 0/1): standalone double-bin partition (legacy padded form) ----
__global__ __launch_bounds__(512) void partition_kernel(
    const int* __restrict__ src, const int* __restrict__ dst,
    int* __restrict__ hs, int* __restrict__ gcursor, int* __restrict__ gcursor2,
    unsigned int* __restrict__ gp_main, unsigned int* __restrict__ gp_last,
    unsigned short* __restrict__ srcpk,
    int* __restrict__ ofl_cnt, unsigned int* __restrict__ ofl, int ofl_cap,
    int* __restrict__ ofl2_cnt, unsigned int* __restrict__ ofl2, int ofl2_cap,
    int nb, int n_edges, int degmode) {
    __shared__ int lcnt[NBMAX], lbase[NBMAX], lcur[NBMAX], lgres[NBMAX];
    __shared__ int mcnt[NBMAX], mbase[NBMAX], mcur[NBMAX], mgres[NBMAX];
    __shared__ unsigned int sbuf[A_TILE];
    __shared__ unsigned short sbuf2[A_TILE];
    __shared__ int ltot, mtot;
    int t = threadIdx.x;
    int tile = blockIdx.x * A_TILE;

    lcnt[t] = 0; mcnt[t] = 0;
    if (t == 0) { ltot = 0; mtot = 0; }

    int s[8], d[8];
    int e0 = tile + t * 8;
    #pragma unroll
    for (int j = 0; j < 2; ++j) {
        int e = e0 + j * 4;
        if (e + 3 < n_edges) {
            int4 sv = *(const int4*)(src + e);
            int4 dv = *(const int4*)(dst + e);
            s[j*4+0] = sv.x; s[j*4+1] = sv.y; s[j*4+2] = sv.z; s[j*4+3] = sv.w;
            d[j*4+0] = dv.x; d[j*4+1] = dv.y; d[j*4+2] = dv.z; d[j*4+3] = dv.w;
        } else {
            #pragma unroll
            for (int k = 0; k < 4; ++k) {
                int ee = e + k;
                s[j*4+k] = (ee < n_edges) ? src[ee] : -1;
                d[j*4+k] = (ee < n_edges) ? dst[ee] : -1;
            }
        }
    }
    __syncthreads();
    #pragma unroll
    for (int j = 0; j < 8; ++j) {
        if (d[j] >= 0) {
            atomicAdd(&lcnt[d[j] >> BSHIFT], 1);
            if (degmode == 1) atomicAdd(&mcnt[s[j] >> BSHIFT], 1);
            else              atomicAdd(&hs[s[j]], 1);
        }
    }
    __syncthreads();
    int c  = lcnt[t];
    int c2 = mcnt[t];
    int rc  = (c  + 15) & ~15;
    int rc2 = (c2 + 15) & ~15;
    int gr = 0, gr2 = 0;
    if (c  > 0) gr  = atomicAdd(&gcursor[t],  rc);
    if (c2 > 0) gr2 = atomicAdd(&gcursor2[t], rc2);
    int lb  = (c  > 0) ? atomicAdd(&ltot, c)  : 0;
    int lb2 = (c2 > 0) ? atomicAdd(&mtot, c2) : 0;
    lbase[t] = lb;  lcur[t] = lb;
    mbase[t] = lb2; mcur[t] = lb2;
    __syncthreads();
    #pragma unroll
    for (int j = 0; j < 8; ++j) {
        if (d[j] >= 0) {
            int bin = d[j] >> BSHIFT;
            int pos = atomicAdd(&lcur[bin], 1);
            sbuf[pos] = ((unsigned int)d[j] << 16) | (unsigned int)s[j];
            if (degmode == 1) {
                int sbin = s[j] >> BSHIFT;
                int pos2 = atomicAdd(&mcur[sbin], 1);
                sbuf2[pos2] = (unsigned short)s[j];
            }
        }
    }
    lgres[t] = gr; mgres[t] = gr2;
    __syncthreads();
    int m = ltot;
    for (int pos = t; pos < m; pos += 512) {
        unsigned int p = sbuf[pos];
        int bin = (int)(p >> (16 + BSHIFT));
        int gidx = lgres[bin] + (pos - lbase[bin]);
        if (gidx < CAP) {
            unsigned int* gp = (bin == nb - 1) ? gp_last : (gp_main + (size_t)bin * CAP);
            gp[gidx] = p;
        } else {
            int op = atomicAdd(ofl_cnt, 1);
            if (op < ofl_cap) ofl[op] = p;
        }
    }
    int m2 = mtot;
    for (int pos = t; pos < m2; pos += 512) {
        unsigned short v = sbuf2[pos];
        int bin = (int)(v >> BSHIFT);
        int gidx = mgres[bin] + (pos - mbase[bin]);
        if (gidx < CAP2) {
            srcpk[(size_t)bin * CAP2 + gidx] = v;
        } else {
            int op = atomicAdd(ofl2_cnt, 1);
            if (op < ofl2_cap) ofl2[op] = (unsigned int)v;
        }
    }
    for (int i = c; i < rc; ++i) {
        int g = gr + i;
        if (g < CAP) {
            unsigned int* gp = (t == nb - 1) ? gp_last : (gp_main + (size_t)t * CAP);
            gp[g] = SENT;
        }
    }
    for (int i = c2; i < rc2; ++i) {
        int g = gr2 + i;
        if (g < CAP2) srcpk[(size_t)t * CAP2 + g] = 0xFFFFu;
    }
}

// ---- K0+K1 fused (mode 2): partition-first, exact reservation, PTILE=8192.
// 16 edges/thread doubles per-bin drain run length (42B->84B: full lines) and
// halves reservation bursts + per-block fixed costs. LDS kept at 40960B
// (4 blocks/CU): sbuf2 eliminated by TEMPORAL reuse of sbuf (edges live in
// registers; sort-by-dst, drain, barrier, sort-by-src into sbuf as u16);
// ltot/mtot live in the never-used bin-511 slots (nodes<=65407 -> bins<=510).
__global__ __launch_bounds__(512) void fused_prep_part_kernel(
    const float* __restrict__ h, const float* __restrict__ W,
    unsigned short* __restrict__ hw, int n_nodes,
    const int* __restrict__ src, const int* __restrict__ dst,
    int* __restrict__ gcursor, int* __restrict__ gcursor2,
    unsigned int* __restrict__ gp_main, unsigned int* __restrict__ gp_last,
    unsigned short* __restrict__ srcpk,
    int* __restrict__ ofl_cnt, unsigned int* __restrict__ ofl, int ofl_cap,
    int* __restrict__ ofl2_cnt, unsigned int* __restrict__ ofl2, int ofl2_cap,
    int nb, int n_edges, int ab, int grid_total) {
    __shared__ int lcnt[NBMAX], ldel[NBMAX];
    __shared__ int mcnt[NBMAX], mdel[NBMAX];
    __shared__ unsigned int sbuf[PTILE];
    int t = threadIdx.x;
    int bid = blockIdx.x;
    if (bid < ab) {
        // ---------------- partition role, tile bid (16 edges/thread) ----------------
        int tile = bid * PTILE;
        lcnt[t] = 0; mcnt[t] = 0;        // bin-511 slots double as ltot/mtot
        int s[16], d[16];
        int e0 = tile + t * 16;
        #pragma unroll
        for (int j = 0; j < 4; ++j) {
            int e = e0 + j * 4;
            if (e + 3 < n_edges) {
                int4 sv = *(const int4*)(src + e);
                int4 dv = *(const int4*)(dst + e);
                s[j*4+0] = sv.x; s[j*4+1] = sv.y; s[j*4+2] = sv.z; s[j*4+3] = sv.w;
                d[j*4+0] = dv.x; d[j*4+1] = dv.y; d[j*4+2] = dv.z; d[j*4+3] = dv.w;
            } else {
                #pragma unroll
                for (int k = 0; k < 4; ++k) {
                    int ee = e + k;
                    s[j*4+k] = (ee < n_edges) ? src[ee] : -1;
                    d[j*4+k] = (ee < n_edges) ? dst[ee] : -1;
                }
            }
        }
        __syncthreads();
        #pragma unroll
        for (int j = 0; j < 16; ++j) {
            if (d[j] >= 0) {
                atomicAdd(&lcnt[d[j] >> BSHIFT], 1);
                atomicAdd(&mcnt[s[j] >> BSHIFT], 1);
            }
        }
        __syncthreads();
        if (t < NBMAX - 1) {                       // bin 511 never holds edges
            int c  = lcnt[t];
            int c2 = mcnt[t];
            int gr = 0, gr2 = 0;
            if (c  > 0) gr  = atomicAdd(&gcursor[t],  c);    // EXACT reservation
            if (c2 > 0) gr2 = atomicAdd(&gcursor2[t], c2);
            int lb  = (c  > 0) ? atomicAdd(&lcnt[NBMAX - 1], c)  : 0;
            int lb2 = (c2 > 0) ? atomicAdd(&mcnt[NBMAX - 1], c2) : 0;
            lcnt[t] = lb;  ldel[t] = gr - lb;      // reuse lcnt as dst sort cursor
            mcnt[t] = lb2; mdel[t] = gr2 - lb2;    // reuse mcnt as src sort cursor
        }
        __syncthreads();
        // dst sort into sbuf (u32, bin-contiguous)
        #pragma unroll
        for (int j = 0; j < 16; ++j) {
            if (d[j] >= 0) {
                int bin = d[j] >> BSHIFT;
                int pos = atomicAdd(&lcnt[bin], 1);
                sbuf[pos] = ((unsigned int)d[j] << 16) | (unsigned int)s[j];
            }
        }
        __syncthreads();
        int m = lcnt[NBMAX - 1];                   // ltot (bin 511 untouched by sort)
        for (int pos = t; pos < m; pos += 512) {
            unsigned int p = sbuf[pos];
            int bin = (int)(p >> (16 + BSHIFT));
            int gidx = pos + ldel[bin];
            if (gidx < CAP) {
                unsigned int* gp = (bin == nb - 1) ? gp_last : (gp_main + (size_t)bin * CAP);
                gp[gidx] = p;
            } else {
                int op = atomicAdd(ofl_cnt, 1);
                if (op < ofl_cap) ofl[op] = p;
            }
        }
        __syncthreads();                           // sbuf fully drained
        // src sort into sbuf reinterpreted as u16 (edges still in registers)
        unsigned short* sb2 = (unsigned short*)sbuf;
        #pragma unroll
        for (int j = 0; j < 16; ++j) {
            if (s[j] >= 0 && d[j] >= 0) {
                int sbin = s[j] >> BSHIFT;
                int pos2 = atomicAdd(&mcnt[sbin], 1);
                sb2[pos2] = (unsigned short)s[j];
            }
        }
        __syncthreads();
        int m2 = mcnt[NBMAX - 1];                  // mtot
        for (int pos = t; pos < m2; pos += 512) {
            unsigned short v = sb2[pos];
            int bin = (int)(v >> BSHIFT);
            int gidx = pos + mdel[bin];
            if (gidx < CAP2) {
                srcpk[(size_t)bin * CAP2 + gidx] = v;
            } else {
                int op = atomicAdd(ofl2_cnt, 1);
                if (op < ofl2_cap) ofl2[op] = (unsigned int)v;
            }
        }
        // dense regions: no sentinel padding
    } else {
        // ---------------- prep role, prep_idx = bid - ab ----------------
        int prep_idx = bid - ab;
        int gid = prep_idx * 512 + t;
        int S = n_nodes + ZPAD;
        if (gid < 16) {
            ((unsigned int*)hw)[(size_t)n_nodes * 16 + gid] = 0u;
        } else if (gid < 32) {
            ((unsigned int*)hw)[(size_t)S * 16 + (size_t)n_nodes * 16 + (gid - 16)] = 0u;
        }
        int lane = t & 63;
        int wv = __builtin_amdgcn_readfirstlane(t >> 6);
        float wcol[D];
        #pragma unroll
        for (int k = 0; k < D; ++k) wcol[k] = W[k * D + lane];
        unsigned short* half0 = hw;
        unsigned short* half1 = hw + (size_t)S * 32;
        int row0 = (prep_idx * 8 + wv) * 4;
        if (row0 >= n_nodes) return;
        const float4* hr = (const float4*)(h + (size_t)row0 * D);   // wave-uniform
        float a0a = 0.f, a0b = 0.f, a1a = 0.f, a1b = 0.f;
        float a2a = 0.f, a2b = 0.f, a3a = 0.f, a3b = 0.f;
        if (row0 + 4 <= n_nodes) {
            #pragma unroll
            for (int k4 = 0; k4 < 16; ++k4) {
                float4 v0 = hr[k4];
                float4 v1 = hr[16 + k4];
                float4 v2 = hr[32 + k4];
                float4 v3 = hr[48 + k4];
                a0a = fmaf(v0.x, wcol[4*k4+0], a0a); a0b = fmaf(v0.y, wcol[4*k4+1], a0b);
                a0a = fmaf(v0.z, wcol[4*k4+2], a0a); a0b = fmaf(v0.w, wcol[4*k4+3], a0b);
                a1a = fmaf(v1.x, wcol[4*k4+0], a1a); a1b = fmaf(v1.y, wcol[4*k4+1], a1b);
                a1a = fmaf(v1.z, wcol[4*k4+2], a1a); a1b = fmaf(v1.w, wcol[4*k4+3], a1b);
                a2a = fmaf(v2.x, wcol[4*k4+0], a2a); a2b = fmaf(v2.y, wcol[4*k4+1], a2b);
                a2a = fmaf(v2.z, wcol[4*k4+2], a2a); a2b = fmaf(v2.w, wcol[4*k4+3], a2b);
                a3a = fmaf(v3.x, wcol[4*k4+0], a3a); a3b = fmaf(v3.y, wcol[4*k4+1], a3b);
                a3a = fmaf(v3.z, wcol[4*k4+2], a3a); a3b = fmaf(v3.w, wcol[4*k4+3], a3b);
            }
            unsigned short r0 = f2bf(a0a + a0b);
            unsigned short r1 = f2bf(a1a + a1b);
            unsigned short r2 = f2bf(a2a + a2b);
            unsigned short r3 = f2bf(a3a + a3b);
            if (lane < 32) {
                half0[(size_t)(row0 + 0) * 32 + lane] = r0;
                half0[(size_t)(row0 + 1) * 32 + lane] = r1;
                half0[(size_t)(row0 + 2) * 32 + lane] = r2;
                half0[(size_t)(row0 + 3) * 32 + lane] = r3;
            } else {
                half1[(size_t)(row0 + 0) * 32 + lane - 32] = r0;
                half1[(size_t)(row0 + 1) * 32 + lane - 32] = r1;
                half1[(size_t)(row0 + 2) * 32 + lane - 32] = r2;
                half1[(size_t)(row0 + 3) * 32 + lane - 32] = r3;
            }
        } else {
            for (int r = 0; r < 4; ++r) {
                int row = row0 + r;
                if (row >= n_nodes) break;
                float aa = 0.f, ab2 = 0.f;
                #pragma unroll
                for (int k4 = 0; k4 < 16; ++k4) {
                    float4 v = hr[r * 16 + k4];
                    aa = fmaf(v.x, wcol[4*k4+0], aa); ab2 = fmaf(v.y, wcol[4*k4+1], ab2);
                    aa = fmaf(v.z, wcol[4*k4+2], aa); ab2 = fmaf(v.w, wcol[4*k4+3], ab2);
                }
                unsigned short val = f2bf(aa + ab2);
                if (lane < 32) half0[(size_t)row * 32 + lane] = val;
                else           half1[(size_t)row * 32 + lane - 32] = val;
            }
        }
    }
}

// ---- K1b (mode 1): out-degree from srcpk regions ----
__global__ __launch_bounds__(512) void deg_from_srcpk(
    const int* __restrict__ gcursor2, const unsigned short* __restrict__ srcpk,
    const int* __restrict__ ofl2_cnt_p, const unsigned int* __restrict__ ofl2, int ofl2_cap,
    int* __restrict__ deg, int nb, int n_nodes) {
    __shared__ int hist[NPB];
    int t = threadIdx.x;
    int b = blockIdx.x;
    if (t < NPB) hist[t] = 0;
    __syncthreads();
    int cnt2 = gcursor2[b]; if (cnt2 > CAP2) cnt2 = CAP2;
    const unsigned short* r2 = srcpk + (size_t)b * CAP2;
    for (int i = t; i < cnt2; i += 512) {
        unsigned short v = r2[i];
        if (v != 0xFFFFu) atomicAdd(&hist[v & (NPB - 1)], 1);
    }
    int n2 = *ofl2_cnt_p; if (n2 < 0) n2 = 0; if (n2 > ofl2_cap) n2 = ofl2_cap;
    for (int i = t; i < n2; i += 512) {
        unsigned int v = ofl2[i];
        if ((int)(v >> BSHIFT) == b) atomicAdd(&hist[v & (NPB - 1)], 1);
    }
    __syncthreads();
    if (t < NPB) {
        int node = b * NPB + t;
        if (node < n_nodes) deg[node] = hist[t];
    }
}

// ---- K1b+K1c fused (mode 2): deg hist + node-sorted padded CSR, one block/bucket.
// Regions are dense (exact reservation) — every entry is a real edge.
__global__ __launch_bounds__(512) void fused_deg_csr_kernel(
    const int* __restrict__ gcursor2, const unsigned short* __restrict__ srcpk,
    const int* __restrict__ ofl2_cnt_p, const unsigned int* __restrict__ ofl2, int ofl2_cap,
    int* __restrict__ deg,
    const int* __restrict__ gcursor,
    const unsigned int* gp_main, const unsigned int* gp_last,
    const int* __restrict__ ofl_cnt_p, const unsigned int* __restrict__ ofl, int ofl_cap,
    unsigned short* __restrict__ gcsr,
    int* __restrict__ nodeoff, int* __restrict__ nodecnt,
    int nb, int n_nodes) {
    __shared__ int hist[NPB];
    __shared__ int lcnt[NPB], loff[NPB], lcur[NPB], lpc[NPB];
    __shared__ unsigned short csr[CAP2];
    int t = threadIdx.x;
    int lane = t & 63;
    int wv = t >> 6;
    int b = blockIdx.x;

    if (t < NPB) { hist[t] = 0; lcnt[t] = 0; }
    __syncthreads();

    int cnt2 = gcursor2[b]; if (cnt2 > CAP2) cnt2 = CAP2;
    const unsigned short* r2 = srcpk + (size_t)b * CAP2;
    for (int i = t; i < cnt2; i += 512) {
        unsigned short v = r2[i];
        atomicAdd(&hist[v & (NPB - 1)], 1);
    }
    int n2 = *ofl2_cnt_p; if (n2 < 0) n2 = 0; if (n2 > ofl2_cap) n2 = ofl2_cap;
    for (int i = t; i < n2; i += 512) {
        unsigned int v = ofl2[i];
        if ((int)(v >> BSHIFT) == b) atomicAdd(&hist[v & (NPB - 1)], 1);
    }

    const unsigned int* region = (b == nb - 1) ? gp_last : (gp_main + (size_t)b * CAP);
    int cnt = gcursor[b]; if (cnt > CAP) cnt = CAP;
    int ofn = *ofl_cnt_p; if (ofn < 0) ofn = 0; if (ofn > ofl_cap) ofn = ofl_cap;
    unsigned int ep[EPT];
    #pragma unroll
    for (int u = 0; u < EPT; ++u) {
        int i = t + u * 512;
        ep[u] = (i < cnt) ? region[i] : SENT;
    }
    #pragma unroll
    for (int u = 0; u < EPT; ++u) {
        if (ep[u] != SENT)
            atomicAdd(&lcnt[(ep[u] >> 16) & (NPB - 1)], 1);
    }
    for (int i = t; i < ofn; i += 512) {
        unsigned int p = ofl[i];
        if ((int)(p >> (16 + BSHIFT)) == b)
            atomicAdd(&lcnt[(p >> 16) & (NPB - 1)], 1);
    }
    __syncthreads();

    if (t < NPB) {
        int node = b * NPB + t;
        if (node < n_nodes) deg[node] = hist[t];
    }

    if (wv == 0) {
        int c0 = lcnt[lane];
        int c1 = lcnt[lane + 64];
        int p0 = (c0 + 15) & ~15;
        int p1 = (c1 + 15) & ~15;
        int sm = p0 + p1;
        int x = sm;
        #pragma unroll
        for (int o = 1; o < 64; o <<= 1) {
            int y = __shfl_up(x, o);
            if (lane >= o) x += y;
        }
        int base = x - sm;
        loff[lane] = base;            lcur[lane] = base;            lpc[lane] = p0;
        loff[lane + 64] = base + p0;  lcur[lane + 64] = base + p0;  lpc[lane + 64] = p1;
    }
    __syncthreads();
    if (t < NPB) {
        nodeoff[(size_t)b * NPB + t] = loff[t];
        nodecnt[(size_t)b * NPB + t] = lpc[t];
    }
    #pragma unroll
    for (int u = 0; u < EPT; ++u) {
        if (ep[u] != SENT) {
            int nl = (int)((ep[u] >> 16) & (NPB - 1));
            int pos = atomicAdd(&lcur[nl], 1);
            if (pos < CAP2) csr[pos] = (unsigned short)(ep[u] & 0xFFFFu);
        }
    }
    for (int i = t; i < ofn; i += 512) {
        unsigned int p = ofl[i];
        if ((int)(p >> (16 + BSHIFT)) == b) {
            int nl = (int)((p >> 16) & (NPB - 1));
            int pos = atomicAdd(&lcur[nl], 1);
            if (pos < CAP2) csr[pos] = (unsigned short)(p & 0xFFFFu);
        }
    }
    __syncthreads();
    if (t < NPB) {                                 // zero-row padding fill
        int i0 = loff[t] + lcnt[t];
        int i1 = loff[t] + lpc[t];
        for (int i = i0; i < i1; ++i)
            if (i < CAP2) csr[i] = (unsigned short)n_nodes;
    }
    __syncthreads();
    int tot = loff[NPB - 1] + lpc[NPB - 1];
    if (tot > CAP2) tot = CAP2;
    unsigned int* gc = (unsigned int*)(gcsr + (size_t)b * CAP2);
    const unsigned int* lc4 = (const unsigned int*)csr;
    for (int i = t; i < (tot + 1) / 2; i += 512) gc[i] = lc4[i];
}

// ---- K2 (mode 2): predicate-free CSR gather; BOTH passes in one dispatch ----
__global__ __launch_bounds__(512, 2) void gather_csr_kernel(
    const unsigned short* __restrict__ hw, const float* __restrict__ bias,
    const int* __restrict__ degarr,
    const unsigned short* __restrict__ gcsr,
    const int* __restrict__ nodeoff, const int* __restrict__ nodecnt,
    int nb, float* __restrict__ out, int n_nodes) {
    __shared__ unsigned short csr[CAP2];
    __shared__ int lo[32], lc[32];
    int t = threadIdx.x;
    int lane = t & 63;
    int wv = t >> 6;
    int g = lane >> 3;
    int l8 = lane & 7;
    int blk = blockIdx.x;
    int half_n = nb * 4;
    int pass = (blk >= half_n) ? 1 : 0;
    int r = blk - pass * half_n;
    int b = r >> 2;
    int hh = r & 3;
    int S = n_nodes + ZPAD;

    int idx0 = b * NPB + hh * 32;
    int base = nodeoff[idx0];
    int end  = nodeoff[idx0 + 31] + nodecnt[idx0 + 31];
    if (base > CAP2) base = CAP2;
    if (end > CAP2) end = CAP2;
    int len = end - base; if (len < 0) len = 0;
    const unsigned int* gc = (const unsigned int*)(gcsr + (size_t)b * CAP2 + base);
    unsigned int* lc4 = (unsigned int*)csr;
    for (int i = t; i < (len + 1) / 2; i += 512) lc4[i] = gc[i];
    if (t < 32) {
        int idx = idx0 + t;
        int off = nodeoff[idx] - base;
        int pc = nodecnt[idx];
        if (off < 0) off = 0;
        if (off > len) off = len;
        if (pc > len - off) pc = (len - off) & ~15;
        if (pc < 0) pc = 0;
        lo[t] = off; lc[t] = pc;
    }
    __syncthreads();

    int pair = wv * 4 + (g >> 1);
    int off = lo[pair];
    int pc = lc[pair];
    float acc[4];
    acc[0] = acc[1] = acc[2] = acc[3] = 0.f;

    const uint2* hwh = (const uint2*)(hw + (size_t)pass * S * 32);
    for (int j = (g & 1) * 8; j < pc; j += 16) {
        uint2 v[8];
        #pragma unroll
        for (int u = 0; u < 8; ++u) {
            int ss = (int)csr[off + j + u];
            v[u] = hwh[(unsigned)(ss * 8 + l8)];
        }
        #pragma unroll
        for (int u = 0; u < 8; ++u) {
            acc[0] += bflo(v[u].x); acc[1] += bfhi(v[u].x);
            acc[2] += bflo(v[u].y); acc[3] += bfhi(v[u].y);
        }
    }

    #pragma unroll
    for (int q = 0; q < 4; ++q)
        acc[q] += __shfl_xor(acc[q], 8);

    if (!(g & 1)) {
        int node = b * NPB + hh * 32 + pair;
        if (node < n_nodes) {
            float4 bv = ((const float4*)bias)[pass * 8 + l8];
            float nrm = rsqrtf((float)degarr[node]);
            float4 rr;
            rr.x = fmaxf(fmaf(acc[0], nrm, bv.x), 0.f);
            rr.y = fmaxf(fmaf(acc[1], nrm, bv.y), 0.f);
            rr.z = fmaxf(fmaf(acc[2], nrm, bv.z), 0.f);
            rr.w = fmaxf(fmaf(acc[3], nrm, bv.w), 0.f);
            ((float4*)out)[(size_t)node * 16 + pass * 8 + l8] = rr;
        }
    }
}

// ---- old combined gather (modes 0/1 only; padded regions with SENT) ----
template<int NLOC>
__global__ __launch_bounds__(512, 2) void bucket_gather_t(
    const unsigned short* __restrict__ hw, const float* __restrict__ bias,
    const int* __restrict__ gcursor, const int* __restrict__ degarr,
    const unsigned int* gp_main, const unsigned int* gp_last,  // may alias out
    const int* __restrict__ ofl_cnt_p, const unsigned int* __restrict__ ofl, int ofl_cap,
    int nb, float* out, int n_nodes) {
    constexpr int SPB = NPB / NLOC;
    __shared__ int lcnt[NLOC];
    __shared__ int loff[NLOC];
    __shared__ int lcur[NLOC];
    __shared__ unsigned short csr[ECAP];
    int t = threadIdx.x;
    int lane = t & 63;
    int wv = t >> 6;
    int g = lane >> 3;
    int l8 = lane & 7;
    int blk = blockIdx.x;
    int b = blk / SPB;
    int hh = blk % SPB;
    int S = n_nodes + ZPAD;
    const unsigned int* region = (b == nb - 1) ? gp_last : (gp_main + (size_t)b * CAP);
    int cnt = gcursor[b]; if (cnt > CAP) cnt = CAP;
    int ofn = *ofl_cnt_p; if (ofn < 0) ofn = 0; if (ofn > ofl_cap) ofn = ofl_cap;

    constexpr int KN = NLOC / 64;
    float acc[KN][2][4];
    #pragma unroll
    for (int k = 0; k < KN; ++k)
        #pragma unroll
        for (int p = 0; p < 2; ++p)
            #pragma unroll
            for (int q = 0; q < 4; ++q) acc[k][p][q] = 0.f;

    int nch = 1 + ((ofn > 0) ? (ofn + ECAP - 1) / ECAP : 0);
    for (int ch = 0; ch < nch; ++ch) {
        const unsigned int* sp; int m;
        if (ch == 0) { sp = region; m = cnt; }
        else {
            sp = ofl + (size_t)(ch - 1) * ECAP;
            m = ofn - (ch - 1) * ECAP; if (m > ECAP) m = ECAP;
        }
        if (t < NLOC) lcnt[t] = 0;
        __syncthreads();
        unsigned int ep[EPT];
        #pragma unroll
        for (int u = 0; u < EPT; ++u) {
            int i = t + u * 512;
            ep[u] = (i < m) ? sp[i] : SENT;
        }
        #pragma unroll
        for (int u = 0; u < EPT; ++u) {
            if (ep[u] != SENT) {
                int pb = (int)(ep[u] >> (16 + BSHIFT));
                int nl_r = (int)((ep[u] >> 16) & (NPB - 1));
                if (pb != b || (SPB == 2 && ((nl_r >> 6) != hh))) ep[u] = SENT;
            }
        }
        #pragma unroll
        for (int u = 0; u < EPT; ++u)
            if (ep[u] != SENT)
                atomicAdd(&lcnt[(ep[u] >> 16) & (NLOC - 1)], 1);
        __syncthreads();
        if (wv == 0) {
            if (NLOC == 128) {
                int v0 = lcnt[lane];
                int v1 = lcnt[lane + 64];
                int sm = v0 + v1;
                int x = sm;
                #pragma unroll
                for (int o = 1; o < 64; o <<= 1) {
                    int y = __shfl_up(x, o);
                    if (lane >= o) x += y;
                }
                int base = x - sm;
                loff[lane] = base;            lcur[lane] = base;
                loff[lane + 64] = base + v0;  lcur[lane + 64] = base + v0;
            } else {
                int v = lcnt[lane];
                int x = v;
                #pragma unroll
                for (int o = 1; o < 64; o <<= 1) {
                    int y = __shfl_up(x, o);
                    if (lane >= o) x += y;
                }
                loff[lane] = x - v;
                lcur[lane] = x - v;
            }
        }
        __syncthreads();
        #pragma unroll
        for (int u = 0; u < EPT; ++u)
            if (ep[u] != SENT) {
                int nl = (int)((ep[u] >> 16) & (NLOC - 1));
                int pos = atomicAdd(&lcur[nl], 1);
                csr[pos] = (unsigned short)(ep[u] & 0xFFFFu);
            }
        __syncthreads();
        #pragma unroll
        for (int p = 0; p < 2; ++p) {
            const uint2* hwh = (const uint2*)(hw + (size_t)p * S * 32);
            #pragma unroll
            for (int k = 0; k < KN; ++k) {
                int nl = k * 64 + wv * 8 + g;
                int off = loff[nl];
                int c = lcnt[nl];
                for (int j = 0; j < c; j += 8) {
                    uint2 v[8];
                    bool ok[8];
                    #pragma unroll
                    for (int u = 0; u < 8; ++u) {
                        int idx = j + u;
                        ok[u] = idx < c;
                        int ss = (int)csr[off + (ok[u] ? idx : 0)];
                        v[u] = ok[u] ? hwh[(size_t)ss * 8 + l8] : make_uint2(0, 0);
                    }
                    #pragma unroll
                    for (int u = 0; u < 8; ++u) {
                        acc[k][p][0] += bflo(v[u].x); acc[k][p][1] += bfhi(v[u].x);
                        acc[k][p][2] += bflo(v[u].y); acc[k][p][3] += bfhi(v[u].y);
                    }
                }
            }
        }
        __syncthreads();
    }

    float4 bv0 = ((const float4*)bias)[l8];
    float4 bv1 = ((const float4*)bias)[8 + l8];
    int node0 = b * NPB + hh * 64;
    #pragma unroll
    for (int k = 0; k < KN; ++k) {
        int nl = k * 64 + wv * 8 + g;
        int node = node0 + nl;
        if (node >= n_nodes) continue;
        float nrm = rsqrtf((float)degarr[node]);
        float4 r0, r1;
        r0.x = fmaxf(fmaf(acc[k][0][0], nrm, bv0.x), 0.f);
        r0.y = fmaxf(fmaf(acc[k][0][1], nrm, bv0.y), 0.f);
        r0.z = fmaxf(fmaf(acc[k][0][2], nrm, bv0.z), 0.f);
        r0.w = fmaxf(fmaf(acc[k][0][3], nrm, bv0.w), 0.f);
        r1.x = fmaxf(fmaf(acc[k][1][0], nrm, bv1.x), 0.f);
        r1.y = fmaxf(fmaf(acc[k][1][1], nrm, bv1.y), 0.f);
        r1.z = fmaxf(fmaf(acc[k][1][2], nrm, bv1.z), 0.f);
        r1.w = fmaxf(fmaf(acc[k][1][3], nrm, bv1.w), 0.f);
        ((float4*)out)[(size_t)node * 16 + l8]     = r0;
        ((float4*)out)[(size_t)node * 16 + 8 + l8] = r1;
    }
}

// ---------------- fallback atomic path (if ws too small / shape odd) ----------------

__global__ void deg_kernel(const int* __restrict__ src, float* __restrict__ deg, int n_edges) {
    int e = blockIdx.x * blockDim.x + threadIdx.x;
    if (e < n_edges) atomicAdd(&deg[src[e]], 1.0f);
}

__global__ void scatter_kernel(const float* __restrict__ h, const int* __restrict__ src,
                               const int* __restrict__ dst, float* __restrict__ agg,
                               int n_edges) {
    long long tid = (long long)blockIdx.x * blockDim.x + threadIdx.x;
    int e = (int)(tid >> 6);
    int f = (int)(tid & 63);
    if (e < n_edges) {
        atomicAdd(&agg[(long long)dst[e] * D + f], h[(long long)src[e] * D + f]);
    }
}

__global__ void transform_kernel(float* __restrict__ agg_out, const float* __restrict__ W,
                                 const float* __restrict__ bias, const float* __restrict__ deg,
                                 int n_nodes) {
    __shared__ float w_lds[D][D];
    __shared__ float a_lds[4][D];
    __shared__ float b_lds[D];
    int t = threadIdx.x;
    for (int i = t; i < D * D; i += 256) w_lds[i >> 6][i & 63] = W[i];
    if (t < D) b_lds[t] = bias[t];
    int rl = t >> 6, col = t & 63;
    int row = blockIdx.x * 4 + rl;
    if (row < n_nodes) a_lds[rl][col] = agg_out[(long long)row * D + col];
    __syncthreads();
    if (row < n_nodes) {
        float sum = 0.f;
        #pragma unroll
        for (int k = 0; k < D; ++k) sum = fmaf(a_lds[rl][k], w_lds[k][col], sum);
        float v = fmaf(sum, rsqrtf(deg[row]), b_lds[col]);
        agg_out[(long long)row * D + col] = fmaxf(v, 0.f);
    }
}

extern "C" void kernel_launch(void* const* d_in, const int* in_sizes, int n_in,
                              void* d_out, int out_size, void* d_ws, size_t ws_size,
                              hipStream_t stream) {
    const float* h    = (const float*)d_in[0];
    const float* W    = (const float*)d_in[1];
    const float* bias = (const float*)d_in[2];
    const int*   src  = (const int*)d_in[3];
    const int*   dst  = (const int*)d_in[4];
    float* out = (float*)d_out;

    int n_nodes = in_sizes[0] / D;
    int n_edges = in_sizes[3];
    int nb = (n_nodes + NPB - 1) / NPB;

    bool shape_ok = (nb <= NBMAX - 1) && (n_nodes <= 65408) && (n_nodes % 2 == 0) &&
                    ((size_t)out_size == (size_t)n_nodes * D);
    size_t head = 2 * (size_t)NBMAX + 2;
    size_t hw_ints = (size_t)(n_nodes + ZPAD) * 32;   // two halves, (n+ZPAD) rows x 32 bf16
    // mode 2: regions in ws, csr path, srcpk deg, nodeoff/cnt
    size_t gp2   = (head + 3) & ~(size_t)3;
    size_t hw2s  = gp2 + (size_t)nb * CAP;
    size_t spk2  = hw2s + hw_ints;
    size_t csr2  = spk2 + (size_t)nb * (CAP2 / 2);    // separate csr store
    size_t ofl2s = csr2 + (size_t)nb * (CAP2 / 2);
    size_t of22s = ofl2s + 16384;
    size_t deg2  = of22s + 8192;
    size_t noff2 = deg2 + n_nodes;
    size_t ncnt2 = noff2 + (size_t)nb * NPB;
    size_t need2 = (ncnt2 + (size_t)nb * NPB) * 4;
    // mode 1: regions alias d_out
    size_t gpl1 = (head + 3) & ~(size_t)3;
    size_t hw1  = gpl1 + CAP;
    size_t spk1 = hw1 + hw_ints;
    size_t ofl1 = spk1 + (size_t)nb * (CAP2 / 2);
    size_t of21 = ofl1 + 16384;
    size_t deg1 = of21 + 8192;
    size_t need1 = (deg1 + n_nodes) * 4;
    // mode 0: legacy global hs, regions alias d_out
    size_t hs0  = head;
    size_t gpl0 = (hs0 + n_nodes + 3) & ~(size_t)3;
    size_t hw0  = gpl0 + CAP;
    size_t ofl0 = hw0 + hw_ints;
    size_t need0 = (ofl0 + 16384) * 4;

    if (shape_ok && ws_size >= need0) {
        int mode = (ws_size >= need2) ? 2 : ((ws_size >= need1) ? 1 : 0);
        int* wsI = (int*)d_ws;
        int* gcursor  = wsI;
        int* gcursor2 = wsI + NBMAX;
        int* ofl_cnt  = wsI + 2 * NBMAX;
        int* ofl2_cnt = wsI + 2 * NBMAX + 1;
        unsigned int* gp_main; unsigned int* gp_last;
        unsigned short* hw; unsigned short* srcpk; unsigned short* gcsrp = 0;
        unsigned int* ofl; unsigned int* ofl2;
        int* degp; int* noffp = 0; int* ncntp = 0; int* hs;
        if (mode == 2) {
            gp_main = (unsigned int*)(wsI + gp2);
            gp_last = gp_main + (size_t)(nb - 1) * CAP;
            hw      = (unsigned short*)(wsI + hw2s);
            srcpk   = (unsigned short*)(wsI + spk2);
            gcsrp   = (unsigned short*)(wsI + csr2);
            ofl     = (unsigned int*)(wsI + ofl2s);
            ofl2    = (unsigned int*)(wsI + of22s);
            degp    = wsI + deg2;
            noffp   = wsI + noff2;
            ncntp   = wsI + ncnt2;
            hs      = gcursor;                   // dummy
        } else if (mode == 1) {
            gp_main = (unsigned int*)d_out;
            gp_last = (unsigned int*)(wsI + gpl1);
            hw      = (unsigned short*)(wsI + hw1);
            srcpk   = (unsigned short*)(wsI + spk1);
            ofl     = (unsigned int*)(wsI + ofl1);
            ofl2    = (unsigned int*)(wsI + of21);
            degp    = wsI + deg1;
            hs      = gcursor;                   // dummy (degmode==1)
        } else {
            gp_main = (unsigned int*)d_out;
            gp_last = (unsigned int*)(wsI + gpl0);
            hw      = (unsigned short*)(wsI + hw0);
            srcpk   = (unsigned short*)(wsI + gpl0);   // unused
            ofl     = (unsigned int*)(wsI + ofl0);
            ofl2    = (unsigned int*)(wsI + ofl0);     // unused
            degp    = wsI + hs0;
            hs      = degp;
        }
        int ofl_cap = 16384, ofl2_cap = (mode >= 1) ? 8192 : 0;

        int pb = (n_nodes + 31) / 32;            // 4 rows/wave x 8 waves
        int ab_legacy = (n_edges + A_TILE - 1) / A_TILE;
        int ab_fused  = (n_edges + PTILE - 1) / PTILE;

        if (mode == 2) {
            zero_head_kernel<<<(int)((head + 511) / 512), 512, 0, stream>>>(wsI, (int)head);
            int grid_total = pb + ab_fused;
            fused_prep_part_kernel<<<grid_total, 512, 0, stream>>>(
                h, W, hw, n_nodes, src, dst, gcursor, gcursor2,
                gp_main, gp_last, srcpk,
                ofl_cnt, ofl, ofl_cap, ofl2_cnt, ofl2, ofl2_cap,
                nb, n_edges, ab_fused, grid_total);
            fused_deg_csr_kernel<<<nb, 512, 0, stream>>>(
                gcursor2, srcpk, ofl2_cnt, ofl2, ofl2_cap, degp,
                gcursor, gp_main, gp_last, ofl_cnt, ofl, ofl_cap,
                gcsrp, noffp, ncntp, nb, n_nodes);
            gather_csr_kernel<<<nb * 8, 512, 0, stream>>>(
                hw, bias, degp, gcsrp, noffp, ncntp, nb, out, n_nodes);
        } else {
            int degmode = (mode >= 1) ? 1 : 0;
            int zc1 = (int)head;
            int zc2 = (mode >= 1) ? 0 : n_nodes;
            int* z2p = (mode >= 1) ? wsI : degp;
            prep_hw_kernel<<<pb, 512, 0, stream>>>(h, W, hw, wsI, zc1, z2p, zc2, n_nodes);
            partition_kernel<<<ab_legacy, 512, 0, stream>>>(src, dst, hs, gcursor, gcursor2,
                                                     gp_main, gp_last, srcpk,
                                                     ofl_cnt, ofl, ofl_cap,
                                                     ofl2_cnt, ofl2, ofl2_cap,
                                                     nb, n_edges, degmode);
            if (mode >= 1)
                deg_from_srcpk<<<nb, 512, 0, stream>>>(gcursor2, srcpk, ofl2_cnt, ofl2,
                                                       ofl2_cap, degp, nb, n_nodes);
            bucket_gather_t<128><<<nb, 512, 0, stream>>>(
                hw, bias, gcursor, degp, gp_main, gp_last,
                ofl_cnt, ofl, ofl_cap, nb, out, n_nodes);
        }
    } else {
        float* deg = (float*)d_ws;
        hipMemsetAsync(out, 0, (size_t)n_nodes * D * sizeof(float), stream);
        hipMemsetAsync(deg, 0, (size_t)n_nodes * sizeof(float), stream);
        int eb = (n_edges + 255) / 256;
        deg_kernel<<<eb, 256, 0, stream>>>(src, deg, n_edges);
        long long total = (long long)n_edges * D;
        scatter_kernel<<<(int)((total + 255) / 256), 256, 0, stream>>>(h, src, dst, out, n_edges);
        transform_kernel<<<(n_nodes + 3) / 4, 256, 0, stream>>>(out, W, bias, deg, n_nodes);
    }
}